// Round 1
// 1032.844 us; speedup vs baseline: 1.2926x; 1.2926x over previous
//
#include <hip/hip_runtime.h>
#include <hip/hip_bf16.h>
#include <stdint.h>

// EncoderLayer: B=4 S=4096 D=1024 H=16 HD=64 HL=8 STRIDE=128 C=32 DFF=4096
// bf16 MFMA internal compute (validated: absmax 0.031 vs 0.109 threshold).
// R7: gemm_bt rewritten as 256-wide-M tile (BM=256, BN=256 or 128), BK=32,
// 512 threads (8 waves 2x4), 4-deep circular LDS buffers with COUNTED
// s_waitcnt vmcnt(N) + raw s_barrier (never drains to 0 in main loop --
// T3/T4 mechanism, m248: +29% at K=1024 over 2-phase). LDS stays in
// fragment order (conflict-free by construction, no swizzle needed).
// FFN2 uses BN=128 so its grid is 256 blocks (exactly 1 full pass).

typedef unsigned short bf16_t;
typedef __attribute__((ext_vector_type(8))) short short8;
typedef __attribute__((ext_vector_type(4))) float v4f;

static __device__ __forceinline__ unsigned short f2b(float f) {
    unsigned int x = __float_as_uint(f);
    x += 0x7fffu + ((x >> 16) & 1u);   // RNE
    return (unsigned short)(x >> 16);
}
static __device__ __forceinline__ float b2f(unsigned short u) {
    return __uint_as_float(((unsigned int)u) << 16);
}

// async global->LDS 16B: LDS dest is wave-uniform base + lane*16
static __device__ __forceinline__ void gload16(const void* g, void* l) {
    __builtin_amdgcn_global_load_lds(
        (const __attribute__((address_space(1))) uint32_t*)g,
        (__attribute__((address_space(3))) uint32_t*)l, 16, 0, 0);
}

template<int N>
static __device__ __forceinline__ void vmwait() {
    asm volatile("s_waitcnt vmcnt(%0)" :: "n"(N) : "memory");
}

// ---------------- converts ----------------

__global__ __launch_bounds__(256) void transpose_convert(
    const float* __restrict__ W, bf16_t* __restrict__ Wt, int K, int N) {
    __shared__ float tile[32][33];
    int n0 = blockIdx.x * 32, k0 = blockIdx.y * 32;
    int tx = threadIdx.x, ty = threadIdx.y;
    for (int i = ty; i < 32; i += 8)
        tile[i][tx] = W[(size_t)(k0 + i) * N + n0 + tx];
    __syncthreads();
    for (int i = ty; i < 32; i += 8)
        Wt[(size_t)(n0 + i) * K + k0 + tx] = f2b(tile[tx][i]);
}

__global__ __launch_bounds__(256) void f32_to_bf16_vec(
    const float* __restrict__ in, bf16_t* __restrict__ out, int n4) {
    int i = blockIdx.x * blockDim.x + threadIdx.x;
    if (i >= n4) return;
    float4 v = ((const float4*)in)[i];
    uint2 p;
    p.x = (unsigned)f2b(v.x) | ((unsigned)f2b(v.y) << 16);
    p.y = (unsigned)f2b(v.z) | ((unsigned)f2b(v.w) << 16);
    ((uint2*)out)[i] = p;
}

// ---------------- GEMM: C[M][N] = A[M][K] @ Bt[N][K]^T + bias (+res)(+relu) ---------
// BM=256 fixed, BN template (256 or 128). BK=32. 512 threads = 8 waves (2 M x 4 N),
// each wave owns 128 x BN/4 of C: acc[8][BN/64] of 16x16 fragments.
// LDS: 4 circular buffers of one K-tile each (A 16KB + B BN/8 KB), frag-order.
// Schedule per iter: vmcnt(counted) -> s_barrier -> ds_read frags -> issue
// stage(it+3) -> MFMA cluster (setprio 1). Loads for tiles it+1..it+3 stay in
// flight across the barrier; epilogue iters drain LPT -> 0.
template<int BN>
__global__ __launch_bounds__(512, 2) void gemm_bt(
    const bf16_t* __restrict__ A, const bf16_t* __restrict__ Bt,
    const float* __restrict__ bias, const float* __restrict__ bias2,
    const float* __restrict__ bias3, const float* __restrict__ resf,
    const bf16_t* __restrict__ resb, float* __restrict__ Cf,
    bf16_t* __restrict__ Cb, int N, int K, int relu) {
    constexpr int N_REP = BN / 64;     // fB frags per wave
    constexpr int BLD = BN / 128;      // B staging passes (512 units each)
    constexpr int LPT = 2 + BLD;       // gload16 per thread per K-tile
    constexpr int ASH = 8192;          // A-tile shorts (256x32)
    constexpr int TSH = ASH + BN * 32; // shorts per buffer
    __shared__ bf16_t lds[4][TSH];

    int t = threadIdx.x;
    int lane = t & 63;
    int wave = t >> 6;
    int wm = (wave >> 2) * 128;        // warp_m in {0,1}
    int wn = (wave & 3) * (BN / 4);    // warp_n in {0..3}
    int m0 = blockIdx.x * 256, n0 = blockIdx.y * BN;

    // hoisted per-thread staging offsets (frag-order layout):
    // unit u: frag-block fb=u>>6 (16 rows), lane l=u&63 holds
    // row fb*16+(l&15), k-group (l>>4)*8 -- exactly the MFMA operand layout,
    // so ds_read is base + lane*16B: conflict-free, no swizzle needed.
    size_t aoff[2]; int adst[2];
#pragma unroll
    for (int p = 0; p < 2; ++p) {
        int u = p * 512 + t;
        int row = ((u >> 6) << 4) + (lane & 15);
        int kk = ((u >> 4) & 3) * 8;
        aoff[p] = (size_t)(m0 + row) * K + kk;
        adst[p] = (u & ~63) * 8;
    }
    size_t boff[BLD]; int bdst[BLD];
#pragma unroll
    for (int p = 0; p < BLD; ++p) {
        int u = p * 512 + t;
        int row = ((u >> 6) << 4) + (lane & 15);
        int kk = ((u >> 4) & 3) * 8;
        boff[p] = (size_t)(n0 + row) * K + kk;
        bdst[p] = (u & ~63) * 8;
    }

    auto stage = [&](int buf, int kt) {
        int k0 = kt * 32;
#pragma unroll
        for (int p = 0; p < 2; ++p)
            gload16(A + aoff[p] + k0, &lds[buf][adst[p]]);
#pragma unroll
        for (int p = 0; p < BLD; ++p)
            gload16(Bt + boff[p] + k0, &lds[buf][ASH + bdst[p]]);
    };

    v4f acc[8][N_REP];
#pragma unroll
    for (int i = 0; i < 8; ++i)
#pragma unroll
        for (int j = 0; j < N_REP; ++j) acc[i][j] = {0.f, 0.f, 0.f, 0.f};

    int NT = K >> 5;
    stage(0, 0); stage(1, 1); stage(2, 2);

    int aro = (wm >> 4) * 512 + lane * 8;          // warp_m*8 frag-blocks in
    int bro = ASH + (wn >> 4) * 512 + lane * 8;    // shorts (512 per block)

    for (int it = 0; it < NT; ++it) {
        // counted wait: tile `it` landed iff only the 2 newest tiles may be
        // outstanding. Tail drains LPT -> 0 (uniform branches).
        int ahead = NT - 1 - it;
        if (ahead >= 2) vmwait<2 * LPT>();
        else if (ahead == 1) vmwait<LPT>();
        else vmwait<0>();
        __builtin_amdgcn_s_barrier();
        __builtin_amdgcn_sched_barrier(0);

        int cb = it & 3;
        short8 fA[8], fB[N_REP];
#pragma unroll
        for (int i = 0; i < 8; ++i)
            fA[i] = *(const short8*)&lds[cb][aro + i * 512];
#pragma unroll
        for (int j = 0; j < N_REP; ++j)
            fB[j] = *(const short8*)&lds[cb][bro + j * 512];

        // prefetch tile it+3 into buf[(it+3)&3] = buf[(it-1)&3]: its last
        // reads completed before this iter's barrier (lgkm drained by MFMA
        // use), so the async writes cannot race any reader.
        if (it + 3 < NT) stage((it + 3) & 3, it + 3);

        __builtin_amdgcn_s_setprio(1);
#pragma unroll
        for (int i = 0; i < 8; ++i)
#pragma unroll
            for (int j = 0; j < N_REP; ++j)
                acc[i][j] = __builtin_amdgcn_mfma_f32_16x16x32_bf16(fA[i], fB[j], acc[i][j], 0, 0, 0);
        __builtin_amdgcn_s_setprio(0);
    }

    // ---- epilogue ----
    int qrow = (lane >> 4) * 4;
    int c15 = lane & 15;
#pragma unroll
    for (int i = 0; i < 8; ++i) {
#pragma unroll
        for (int j = 0; j < N_REP; ++j) {
            int col = n0 + wn + j * 16 + c15;
            float bval;
            if (bias2) {
                int seg = col >> 10;
                const float* bp = seg == 0 ? bias : (seg == 1 ? bias2 : bias3);
                bval = bp[col & 1023];
            } else {
                bval = bias[col];
            }
#pragma unroll
            for (int r = 0; r < 4; ++r) {
                int row = m0 + wm + i * 16 + qrow + r;
                size_t idx = (size_t)row * N + col;
                float val = acc[i][j][r] + bval;
                if (resf) val += resf[idx];
                if (resb) val += b2f(resb[idx]);
                if (relu) val = fmaxf(val, 0.f);
                if (Cf) Cf[idx] = val;
                if (Cb) Cb[idx] = f2b(val);
            }
        }
    }
}

// ---------------- MFMA flash attention (r3-validated) ----------------
// qkv is interleaved [tok][3072]: q at +0, k at +1024, v at +2048.
template<int NCHUNK, bool GLOBAL>
__global__ __launch_bounds__(256) void mfma_attn(
    const bf16_t* __restrict__ qkv, bf16_t* __restrict__ o, int head_base) {
    __shared__ bf16_t buf[32768];                  // 64 KB
    bf16_t* ldsQ  = buf;                           // 16 KB, dead after preload
    bf16_t* ldsP  = buf;                           // 32 KB, aliases ldsQ
    bf16_t* ldsK  = buf + 16384;                   // 16 KB
    bf16_t* ldsVt = buf + 24576;                   // 16 KB

    int qc = blockIdx.x, hh = blockIdx.y, b = blockIdx.z;
    int h = head_base + hh;
    int t = threadIdx.x, lane = t & 63, w = t >> 6;
    int quad = lane >> 4, c15 = lane & 15;
    size_t base = (size_t)b * 4096 * 3072 + (size_t)h * 64;

    // ---- stage Q in A-frag order: unit = s*512 + mt*64 + qq*16 + l15 ----
#pragma unroll
    for (int u = t; u < 1024; u += 256) {
        int s = u >> 9, mt = (u >> 6) & 7, qq = (u >> 4) & 3, l = u & 15;
        int tok = qc * 128 + mt * 16 + l;
        gload16(qkv + base + (size_t)tok * 3072 + s * 32 + qq * 8, ldsQ + (u & ~63) * 8);
    }
    __syncthreads();

    short8 fQ[2][2];
#pragma unroll
    for (int i = 0; i < 2; ++i)
#pragma unroll
        for (int s = 0; s < 2; ++s)
            fQ[i][s] = *(const short8*)(ldsQ + (s * 512 + (w * 2 + i) * 64 + lane) * 8);

    v4f oacc[2][4];
    float lacc[2][4];
#pragma unroll
    for (int i = 0; i < 2; ++i)
#pragma unroll
        for (int n = 0; n < 4; ++n) oacc[i][n] = {0.f, 0.f, 0.f, 0.f};
#pragma unroll
    for (int i = 0; i < 2; ++i)
#pragma unroll
        for (int r = 0; r < 4; ++r) lacc[i][r] = 0.f;

    for (int c = 0; c < NCHUNK; ++c) {
        __syncthreads();   // fences fQ preload reads vs ldsP writes (chunk 0)
        // ---- stage K in Bt-frag order (n=key, k=d), async ----
#pragma unroll
        for (int u = t; u < 1024; u += 256) {
            int s = u >> 9, nt = (u >> 6) & 7, qq = (u >> 4) & 3, l = u & 15;
            int key = c * 128 + nt * 16 + l;
            int tok = GLOBAL ? ((key >> 5) * 128 + 96 + (key & 31)) : (qc * 128 + key);
            gload16(qkv + base + 1024 + (size_t)tok * 3072 + s * 32 + qq * 8, ldsK + (u & ~63) * 8);
        }
        // ---- stage V^T in Bt-frag order (n=d, k=key): gather transpose ----
#pragma unroll
        for (int u = t; u < 1024; u += 256) {
            int tt = u >> 8, nt = (u >> 6) & 3, qq = (u >> 4) & 3, l = u & 15;
            int d = nt * 16 + l;
            int key0 = c * 128 + tt * 32 + qq * 8;
            int tok0 = GLOBAL ? ((key0 >> 5) * 128 + 96 + (key0 & 31)) : (qc * 128 + key0);
            const bf16_t* vp = qkv + base + 2048 + (size_t)tok0 * 3072 + d;
            short8 tmp;
#pragma unroll
            for (int jj = 0; jj < 8; ++jj) tmp[jj] = (short)vp[(size_t)jj * 3072];
            *(short8*)(ldsVt + u * 8) = tmp;
        }
        __syncthreads();

        // ---- S = Q K^T ----
        v4f sacc[2][8];
#pragma unroll
        for (int i = 0; i < 2; ++i)
#pragma unroll
            for (int j = 0; j < 8; ++j) sacc[i][j] = {0.f, 0.f, 0.f, 0.f};
#pragma unroll
        for (int s = 0; s < 2; ++s)
#pragma unroll
            for (int j = 0; j < 8; ++j) {
                short8 fK = *(const short8*)(ldsK + (s * 512 + j * 64 + lane) * 8);
#pragma unroll
                for (int i = 0; i < 2; ++i)
                    sacc[i][j] = __builtin_amdgcn_mfma_f32_16x16x32_bf16(fQ[i][s], fK, sacc[i][j], 0, 0, 0);
            }

        // ---- P = exp(S*scale); l += rowsum; P -> ldsP (A-frag, swizzled) ----
#pragma unroll
        for (int i = 0; i < 2; ++i) {
            float rs[4] = {0.f, 0.f, 0.f, 0.f};
#pragma unroll
            for (int j = 0; j < 8; ++j)
#pragma unroll
                for (int r = 0; r < 4; ++r) {
                    float p = __expf(sacc[i][j][r] * 0.125f);
                    sacc[i][j][r] = p;
                    rs[r] += p;
                }
#pragma unroll
            for (int m = 1; m < 16; m <<= 1)
#pragma unroll
                for (int r = 0; r < 4; ++r) rs[r] += __shfl_xor(rs[r], m);
#pragma unroll
            for (int r = 0; r < 4; ++r) lacc[i][r] += rs[r];
#pragma unroll
            for (int j = 0; j < 8; ++j) {
                int tt = j >> 1;
                int qq = (2 * j + (c15 >> 3)) & 3;
#pragma unroll
                for (int r = 0; r < 4; ++r) {
                    int slot = (quad * 4 + r) ^ qq;
                    int unit = (w * 4 + tt) * 128 + i * 64 + qq * 16 + slot;
                    ldsP[unit * 8 + (c15 & 7)] = f2b(sacc[i][j][r]);
                }
            }
        }

        // ---- O += P V (per-wave ldsP region: no barrier needed) ----
#pragma unroll
        for (int tt = 0; tt < 4; ++tt) {
            short8 fP[2];
#pragma unroll
            for (int i = 0; i < 2; ++i)
                fP[i] = *(const short8*)(ldsP + (((w * 4 + tt) * 128 + i * 64
                              + quad * 16 + (c15 ^ quad))) * 8);
#pragma unroll
            for (int n = 0; n < 4; ++n) {
                short8 fV = *(const short8*)(ldsVt + (tt * 256 + n * 64 + lane) * 8);
#pragma unroll
                for (int i = 0; i < 2; ++i)
                    oacc[i][n] = __builtin_amdgcn_mfma_f32_16x16x32_bf16(fP[i], fV, oacc[i][n], 0, 0, 0);
            }
        }
    }

    // ---- epilogue: O / l ----
#pragma unroll
    for (int i = 0; i < 2; ++i)
#pragma unroll
        for (int r = 0; r < 4; ++r) {
            int row = qc * 128 + (w * 2 + i) * 16 + quad * 4 + r;
            float inv = 1.f / lacc[i][r];
            bf16_t* orow = o + ((size_t)b * 4096 + row) * 1024 + h * 64;
#pragma unroll
            for (int n = 0; n < 4; ++n)
                orow[n * 16 + c15] = f2b(oacc[i][n][r] * inv);
        }
}

// ---------------- layernorm (may run in-place) ----------------
__global__ __launch_bounds__(256) void ln_kernel(
    const float* x, const float* g, const float* bta,
    float* outf, bf16_t* outb) {
    int row = blockIdx.x, t = threadIdx.x;
    const float4 vv = ((const float4*)(x + (size_t)row * 1024))[t];
    float s = vv.x + vv.y + vv.z + vv.w;
    float ss = vv.x * vv.x + vv.y * vv.y + vv.z * vv.z + vv.w * vv.w;
    for (int off = 32; off > 0; off >>= 1) {
        s += __shfl_down(s, off);
        ss += __shfl_down(ss, off);
    }
    __shared__ float red[8];
    int wave = t >> 6;
    if ((t & 63) == 0) { red[wave] = s; red[wave + 4] = ss; }
    __syncthreads();
    float ts = red[0] + red[1] + red[2] + red[3];
    float tss = red[4] + red[5] + red[6] + red[7];
    float mu = ts * (1.f / 1024.f);
    float var = tss * (1.f / 1024.f) - mu * mu;
    float rstd = rsqrtf(var + 1e-6f);
    float4 gv = ((const float4*)g)[t];
    float4 bv = ((const float4*)bta)[t];
    float4 ov;
    ov.x = (vv.x - mu) * rstd * gv.x + bv.x;
    ov.y = (vv.y - mu) * rstd * gv.y + bv.y;
    ov.z = (vv.z - mu) * rstd * gv.z + bv.z;
    ov.w = (vv.w - mu) * rstd * gv.w + bv.w;
    if (outf) ((float4*)(outf + (size_t)row * 1024))[t] = ov;
    if (outb) {
        uint2 pk;
        pk.x = (unsigned)f2b(ov.x) | ((unsigned)f2b(ov.y) << 16);
        pk.y = (unsigned)f2b(ov.z) | ((unsigned)f2b(ov.w) << 16);
        ((uint2*)(outb + (size_t)row * 1024))[t] = pk;
    }
}

// ---------------- launch ----------------
extern "C" void kernel_launch(void* const* d_in, const int* in_sizes, int n_in,
                              void* d_out, int out_size, void* d_ws, size_t ws_size,
                              hipStream_t stream) {
    const float* src = (const float*)d_in[0];
    const float* Wq = (const float*)d_in[2];  const float* bq = (const float*)d_in[3];
    const float* Wk = (const float*)d_in[4];  const float* bk = (const float*)d_in[5];
    const float* Wv = (const float*)d_in[6];  const float* bv = (const float*)d_in[7];
    const float* Wo = (const float*)d_in[8];  const float* bo = (const float*)d_in[9];
    const float* g1 = (const float*)d_in[10]; const float* be1 = (const float*)d_in[11];
    const float* W1 = (const float*)d_in[12]; const float* b1 = (const float*)d_in[13];
    const float* W2 = (const float*)d_in[14]; const float* b2 = (const float*)d_in[15];
    const float* g2 = (const float*)d_in[16]; const float* be2 = (const float*)d_in[17];
    float* out = (float*)d_out;   // also the fp32 residual stream (64 MB)
    char* ws = (char*)d_ws;
    const size_t MB = 1ull << 20;

    // layout (MB), peak 152 (ws >= 176 confirmed r5):
    //  [0,32)    xb -> ob -> alnb   (sequential lifetimes)
    //  [32,128)  qkv (96) -> hb (64, chunked FFN)
    //  [128,134) wqkvt  [134,136) wot  [136,144) w1t  [144,152) w2t
    bf16_t* xb    = (bf16_t*)(ws + 0 * MB);
    bf16_t* ob    = (bf16_t*)(ws + 0 * MB);
    bf16_t* alnb  = (bf16_t*)(ws + 0 * MB);
    bf16_t* qkv   = (bf16_t*)(ws + 32 * MB);
    bf16_t* hb    = (bf16_t*)(ws + 32 * MB);
    bf16_t* wqkvt = (bf16_t*)(ws + 128 * MB);
    bf16_t* wot   = (bf16_t*)(ws + 134 * MB);
    bf16_t* w1t   = (bf16_t*)(ws + 136 * MB);
    bf16_t* w2t   = (bf16_t*)(ws + 144 * MB);

    dim3 tb(32, 8);
    transpose_convert<<<dim3(32, 32), tb, 0, stream>>>(Wq, wqkvt, 1024, 1024);
    transpose_convert<<<dim3(32, 32), tb, 0, stream>>>(Wk, wqkvt + 1024 * 1024, 1024, 1024);
    transpose_convert<<<dim3(32, 32), tb, 0, stream>>>(Wv, wqkvt + 2 * 1024 * 1024, 1024, 1024);
    transpose_convert<<<dim3(32, 32), tb, 0, stream>>>(Wo, wot, 1024, 1024);
    transpose_convert<<<dim3(128, 32), tb, 0, stream>>>(W1, w1t, 1024, 4096);
    transpose_convert<<<dim3(32, 128), tb, 0, stream>>>(W2, w2t, 4096, 1024);
    f32_to_bf16_vec<<<16384, 256, 0, stream>>>(src, xb, 4194304);

    // fused QKV: C[M][3072] = xb @ [Wq|Wk|Wv]^T, per-segment bias
    gemm_bt<256><<<dim3(64, 12), 512, 0, stream>>>(xb, wqkvt, bq, bk, bv,
        nullptr, nullptr, nullptr, qkv, 3072, 1024, 0);

    mfma_attn<1, false><<<dim3(32, 8, 4), 256, 0, stream>>>(qkv, ob, 0);
    mfma_attn<8, true ><<<dim3(32, 8, 4), 256, 0, stream>>>(qkv, ob, 8);

    // out-proj + src residual -> out (fp32)
    gemm_bt<256><<<dim3(64, 4), 512, 0, stream>>>(ob, wot, bo, nullptr, nullptr,
        src, nullptr, out, nullptr, 1024, 1024, 0);
    ln_kernel<<<16384, 256, 0, stream>>>(out, g1, be1, nullptr, alnb);

    // FFN in two 8192-row chunks (hb fits in the dead qkv region)
    for (int mc = 0; mc < 2; ++mc) {
        const bf16_t* arows = alnb + (size_t)mc * 8192 * 1024;
        float* yrows = out + (size_t)mc * 8192 * 1024;
        gemm_bt<256><<<dim3(32, 16), 512, 0, stream>>>(arows, w1t, b1, nullptr, nullptr,
            nullptr, nullptr, nullptr, hb, 4096, 1024, 1);
        gemm_bt<128><<<dim3(32, 8), 512, 0, stream>>>(hb, w2t, b2, nullptr, nullptr,
            nullptr, arows, yrows, nullptr, 1024, 4096, 0);
    }
    ln_kernel<<<16384, 256, 0, stream>>>(out, g2, be2, out, nullptr);

    (void)in_sizes; (void)n_in; (void)out_size; (void)ws_size;
}

// Round 3
// 988.846 us; speedup vs baseline: 1.3501x; 1.0445x over previous
//
#include <hip/hip_runtime.h>
#include <hip/hip_bf16.h>
#include <stdint.h>

// EncoderLayer: B=4 S=4096 D=1024 H=16 HD=64 HL=8 STRIDE=128 C=32 DFF=4096
// bf16 MFMA internal compute (validated: absmax 0.031 vs 0.109 threshold).
// R9 == R8 resubmit (container failed twice at infra level; no kernel signal).
// R8: attention rework (r7 counters: global attn 157us, MfmaUtil 8.7%,
// occupancy 11.5% -- latency-stalled on the scalar V gather-transpose).
//  (a) v_transpose prepass: Vt[b][h][d][tok] in ws (local 16MB + global 4MB)
//      so attn V-staging becomes coalesced global_load_lds (no scalar gather).
//  (b) attn K-loop rebuilt like the R7 GEMM: KVBLK=64, 3-deep circular
//      K/Vt LDS buffers (64KB total), ONE s_barrier per chunk, counted
//      vmcnt(4) (never 0 in main loop), stage(c+2) after barrier (targets
//      (c-1)%3 whose readers finished pre-barrier), setprio around MFMA.
// GEMM (R7 structure) unchanged: BM=256, 512 thr, 4-deep counted vmcnt.

typedef unsigned short bf16_t;
typedef __attribute__((ext_vector_type(8))) short short8;
typedef __attribute__((ext_vector_type(4))) float v4f;

static __device__ __forceinline__ unsigned short f2b(float f) {
    unsigned int x = __float_as_uint(f);
    x += 0x7fffu + ((x >> 16) & 1u);   // RNE
    return (unsigned short)(x >> 16);
}
static __device__ __forceinline__ float b2f(unsigned short u) {
    return __uint_as_float(((unsigned int)u) << 16);
}

// async global->LDS 16B: LDS dest is wave-uniform base + lane*16
static __device__ __forceinline__ void gload16(const void* g, void* l) {
    __builtin_amdgcn_global_load_lds(
        (const __attribute__((address_space(1))) uint32_t*)g,
        (__attribute__((address_space(3))) uint32_t*)l, 16, 0, 0);
}

template<int N>
static __device__ __forceinline__ void vmwait() {
    asm volatile("s_waitcnt vmcnt(%0)" :: "n"(N) : "memory");
}
static __device__ __forceinline__ void lgkmwait0() {
    asm volatile("s_waitcnt lgkmcnt(0)" ::: "memory");
}

// ---------------- converts ----------------

__global__ __launch_bounds__(256) void transpose_convert(
    const float* __restrict__ W, bf16_t* __restrict__ Wt, int K, int N) {
    __shared__ float tile[32][33];
    int n0 = blockIdx.x * 32, k0 = blockIdx.y * 32;
    int tx = threadIdx.x, ty = threadIdx.y;
    for (int i = ty; i < 32; i += 8)
        tile[i][tx] = W[(size_t)(k0 + i) * N + n0 + tx];
    __syncthreads();
    for (int i = ty; i < 32; i += 8)
        Wt[(size_t)(n0 + i) * K + k0 + tx] = f2b(tile[tx][i]);
}

__global__ __launch_bounds__(256) void f32_to_bf16_vec(
    const float* __restrict__ in, bf16_t* __restrict__ out, int n4) {
    int i = blockIdx.x * blockDim.x + threadIdx.x;
    if (i >= n4) return;
    float4 v = ((const float4*)in)[i];
    uint2 p;
    p.x = (unsigned)f2b(v.x) | ((unsigned)f2b(v.y) << 16);
    p.y = (unsigned)f2b(v.z) | ((unsigned)f2b(v.w) << 16);
    ((uint2*)out)[i] = p;
}

// ---------------- V transpose prepass ----------------
// Builds vt[(b*8+h)*64 + d][tok'] (bf16) from qkv's V segment, where tok' is
// the compacted key index (identity for local heads, the C=32 tail-of-stride
// gather for global heads). XOR-swizzled LDS tile (row>>3) keeps both phases
// bank-conflict-free at short8 width.
template<bool GLOBAL>
__global__ __launch_bounds__(256) void v_transpose(
    const bf16_t* __restrict__ qkv, bf16_t* __restrict__ vt, int ntok) {
    __shared__ bf16_t tile[4096];
    int tb = blockIdx.x, h = blockIdx.y, b = blockIdx.z;
    int t = threadIdx.x;
    size_t src = (size_t)b * 4096 * 3072 + (size_t)(GLOBAL ? h + 8 : h) * 64 + 2048;
    for (int u = t; u < 512; u += 256) {
        int row = u >> 3, g = u & 7;
        int lt = tb * 64 + row;
        int tok = GLOBAL ? ((lt >> 5) * 128 + 96 + (lt & 31)) : lt;
        short8 vrow = *(const short8*)(qkv + src + (size_t)tok * 3072 + g * 8);
        *(short8*)&tile[(row * 8 + (g ^ (row >> 3))) * 8] = vrow;
    }
    __syncthreads();
    for (int u = t; u < 512; u += 256) {
        int d = u >> 3, t8g = u & 7;
        short8 vcol;
#pragma unroll
        for (int j = 0; j < 8; ++j) {
            int row = t8g * 8 + j;
            vcol[j] = tile[(row * 8 + ((d >> 3) ^ (row >> 3))) * 8 + (d & 7)];
        }
        *(short8*)(vt + ((size_t)(b * 8 + h) * 64 + d) * ntok + (size_t)tb * 64 + t8g * 8) = vcol;
    }
}

// ---------------- GEMM: C[M][N] = A[M][K] @ Bt[N][K]^T + bias (+res)(+relu) ---------
// BM=256 fixed, BN template (256 or 128). BK=32. 512 threads = 8 waves (2 M x 4 N).
// 4 circular LDS K-tile buffers, counted vmcnt, raw s_barrier, setprio MFMA.
template<int BN>
__global__ __launch_bounds__(512, 2) void gemm_bt(
    const bf16_t* __restrict__ A, const bf16_t* __restrict__ Bt,
    const float* __restrict__ bias, const float* __restrict__ bias2,
    const float* __restrict__ bias3, const float* __restrict__ resf,
    const bf16_t* __restrict__ resb, float* __restrict__ Cf,
    bf16_t* __restrict__ Cb, int N, int K, int relu) {
    constexpr int N_REP = BN / 64;     // fB frags per wave
    constexpr int BLD = BN / 128;      // B staging passes (512 units each)
    constexpr int LPT = 2 + BLD;       // gload16 per thread per K-tile
    constexpr int ASH = 8192;          // A-tile shorts (256x32)
    constexpr int TSH = ASH + BN * 32; // shorts per buffer
    __shared__ bf16_t lds[4][TSH];

    int t = threadIdx.x;
    int lane = t & 63;
    int wave = t >> 6;
    int wm = (wave >> 2) * 128;
    int wn = (wave & 3) * (BN / 4);
    int m0 = blockIdx.x * 256, n0 = blockIdx.y * BN;

    size_t aoff[2]; int adst[2];
#pragma unroll
    for (int p = 0; p < 2; ++p) {
        int u = p * 512 + t;
        int row = ((u >> 6) << 4) + (lane & 15);
        int kk = ((u >> 4) & 3) * 8;
        aoff[p] = (size_t)(m0 + row) * K + kk;
        adst[p] = (u & ~63) * 8;
    }
    size_t boff[BLD]; int bdst[BLD];
#pragma unroll
    for (int p = 0; p < BLD; ++p) {
        int u = p * 512 + t;
        int row = ((u >> 6) << 4) + (lane & 15);
        int kk = ((u >> 4) & 3) * 8;
        boff[p] = (size_t)(n0 + row) * K + kk;
        bdst[p] = (u & ~63) * 8;
    }

    auto stage = [&](int buf, int kt) {
        int k0 = kt * 32;
#pragma unroll
        for (int p = 0; p < 2; ++p)
            gload16(A + aoff[p] + k0, &lds[buf][adst[p]]);
#pragma unroll
        for (int p = 0; p < BLD; ++p)
            gload16(Bt + boff[p] + k0, &lds[buf][ASH + bdst[p]]);
    };

    v4f acc[8][N_REP];
#pragma unroll
    for (int i = 0; i < 8; ++i)
#pragma unroll
        for (int j = 0; j < N_REP; ++j) acc[i][j] = {0.f, 0.f, 0.f, 0.f};

    int NT = K >> 5;
    stage(0, 0); stage(1, 1); stage(2, 2);

    int aro = (wm >> 4) * 512 + lane * 8;
    int bro = ASH + (wn >> 4) * 512 + lane * 8;

    for (int it = 0; it < NT; ++it) {
        int ahead = NT - 1 - it;
        if (ahead >= 2) vmwait<2 * LPT>();
        else if (ahead == 1) vmwait<LPT>();
        else vmwait<0>();
        __builtin_amdgcn_s_barrier();
        __builtin_amdgcn_sched_barrier(0);

        int cb = it & 3;
        short8 fA[8], fB[N_REP];
#pragma unroll
        for (int i = 0; i < 8; ++i)
            fA[i] = *(const short8*)&lds[cb][aro + i * 512];
#pragma unroll
        for (int j = 0; j < N_REP; ++j)
            fB[j] = *(const short8*)&lds[cb][bro + j * 512];

        if (it + 3 < NT) stage((it + 3) & 3, it + 3);

        __builtin_amdgcn_s_setprio(1);
#pragma unroll
        for (int i = 0; i < 8; ++i)
#pragma unroll
            for (int j = 0; j < N_REP; ++j)
                acc[i][j] = __builtin_amdgcn_mfma_f32_16x16x32_bf16(fA[i], fB[j], acc[i][j], 0, 0, 0);
        __builtin_amdgcn_s_setprio(0);
    }

    int qrow = (lane >> 4) * 4;
    int c15 = lane & 15;
#pragma unroll
    for (int i = 0; i < 8; ++i) {
#pragma unroll
        for (int j = 0; j < N_REP; ++j) {
            int col = n0 + wn + j * 16 + c15;
            float bval;
            if (bias2) {
                int seg = col >> 10;
                const float* bp = seg == 0 ? bias : (seg == 1 ? bias2 : bias3);
                bval = bp[col & 1023];
            } else {
                bval = bias[col];
            }
#pragma unroll
            for (int r = 0; r < 4; ++r) {
                int row = m0 + wm + i * 16 + qrow + r;
                size_t idx = (size_t)row * N + col;
                float val = acc[i][j][r] + bval;
                if (resf) val += resf[idx];
                if (resb) val += b2f(resb[idx]);
                if (relu) val = fmaxf(val, 0.f);
                if (Cf) Cf[idx] = val;
                if (Cb) Cb[idx] = f2b(val);
            }
        }
    }
}

// ---------------- MFMA flash attention, pipelined ----------------
// qkv interleaved [tok][3072]: q +0, k +1024, v +2048. vt is the prepass
// output [bh*64+d][tok'] (compacted keys). NCHUNK counts 64-key chunks.
// LDS (shorts): [0,8192) Q (preload) aliased by P (128q x 64k A-frag);
//   [8192,20480) K bufs 3 x 4096; [20480,32768) Vt bufs 3 x 4096. 64KB.
template<int NCHUNK, bool GLOBAL>
__global__ __launch_bounds__(256) void mfma_attn(
    const bf16_t* __restrict__ qkv, const bf16_t* __restrict__ vt,
    bf16_t* __restrict__ o, int head_base) {
    __shared__ bf16_t buf[32768];
    bf16_t* ldsQ = buf;
    bf16_t* ldsP = buf;
    constexpr int KB = 8192, VB = 20480;

    int qc = blockIdx.x, hh = blockIdx.y, b = blockIdx.z;
    int h = head_base + hh;
    int t = threadIdx.x, lane = t & 63, w = t >> 6;
    int quad = lane >> 4, c15 = lane & 15;
    size_t base = (size_t)b * 4096 * 3072 + (size_t)h * 64;
    const int NTOK = GLOBAL ? 1024 : 4096;
    size_t vtbase = (size_t)(b * 8 + hh) * 64 * NTOK + (GLOBAL ? 0 : (size_t)qc * 128);
    const int CADV = (GLOBAL ? 256 : 64) * 3072;   // K token advance per chunk

    // ---- staging offsets (frag-order layouts, all gload16) ----
    // K unit u: s=u>>8 (d 32-blk), key16=(u>>6)&3, lane: key=key16*16+(l&15),
    //           d = s*32 + ((l>>4)&3)*8.
    size_t koff[2]; int kdst[2];
#pragma unroll
    for (int p = 0; p < 2; ++p) {
        int u = p * 256 + t;
        int s = u >> 8;
        int kl = ((u >> 6) & 3) * 16 + (lane & 15);
        int dk = s * 32 + ((lane >> 4) & 3) * 8;
        int tok0 = GLOBAL ? ((kl >> 5) * 128 + 96 + (kl & 31)) : (qc * 128 + kl);
        koff[p] = base + 1024 + (size_t)tok0 * 3072 + dk;
        kdst[p] = KB + (u & ~63) * 8;
    }
    // Vt unit u: tt=u>>8 (key 32-tile), n=(u>>6)&3 (d 16-blk), lane:
    //           d = n*16+(l&15), key = tt*32 + ((l>>4)&3)*8.
    size_t voff[2]; int vdst[2];
#pragma unroll
    for (int p = 0; p < 2; ++p) {
        int u = p * 256 + t;
        int dd = ((u >> 6) & 3) * 16 + (lane & 15);
        int kl = (u >> 8) * 32 + ((lane >> 4) & 3) * 8;
        voff[p] = vtbase + (size_t)dd * NTOK + kl;
        vdst[p] = VB + (u & ~63) * 8;
    }

    auto stage = [&](int c) {
        int q = c % 3;
        size_t ka = (size_t)c * CADV;
        size_t va = (size_t)c * 64;
#pragma unroll
        for (int p = 0; p < 2; ++p)
            gload16(qkv + koff[p] + ka, buf + kdst[p] + q * 4096);
#pragma unroll
        for (int p = 0; p < 2; ++p)
            gload16(vt + voff[p] + va, buf + vdst[p] + q * 4096);
    };

    // ---- stage Q in A-frag order ----
#pragma unroll
    for (int u = t; u < 1024; u += 256) {
        int s = u >> 9, mt = (u >> 6) & 7, qq = (u >> 4) & 3, ll = u & 15;
        int tok = qc * 128 + mt * 16 + ll;
        gload16(qkv + base + (size_t)tok * 3072 + s * 32 + qq * 8, ldsQ + (u & ~63) * 8);
    }
    stage(0);
    stage(1);
    vmwait<8>();                       // Q's 4 loads (oldest) landed, all waves
    __builtin_amdgcn_s_barrier();

    short8 fQ[2][2];
#pragma unroll
    for (int i = 0; i < 2; ++i)
#pragma unroll
        for (int s = 0; s < 2; ++s)
            fQ[i][s] = *(const short8*)(ldsQ + (s * 512 + (w * 2 + i) * 64 + lane) * 8);
    lgkmwait0();                       // fQ in regs before P region gets written
    __builtin_amdgcn_sched_barrier(0);

    v4f oacc[2][4];
    float lacc[2][4];
#pragma unroll
    for (int i = 0; i < 2; ++i)
#pragma unroll
        for (int n = 0; n < 4; ++n) oacc[i][n] = {0.f, 0.f, 0.f, 0.f};
#pragma unroll
    for (int i = 0; i < 2; ++i)
#pragma unroll
        for (int r = 0; r < 4; ++r) lacc[i][r] = 0.f;

    for (int c = 0; c < NCHUNK; ++c) {
        // counted wait: chunk c's 4 loads landed; chunk c+1's may remain.
        if (c + 1 < NCHUNK) vmwait<4>();
        else vmwait<0>();
        __builtin_amdgcn_s_barrier();
        __builtin_amdgcn_sched_barrier(0);
        // prefetch chunk c+2 into buf (c+2)%3 == (c-1)%3: its readers
        // (chunk c-1, all waves) finished before this barrier.
        if (c + 2 < NCHUNK) stage(c + 2);

        const bf16_t* Kq = buf + KB + (c % 3) * 4096;
        const bf16_t* Vq = buf + VB + (c % 3) * 4096;

        // ---- S = Q K^T ----
        v4f sacc[2][4];
#pragma unroll
        for (int i = 0; i < 2; ++i)
#pragma unroll
            for (int j = 0; j < 4; ++j) sacc[i][j] = {0.f, 0.f, 0.f, 0.f};
        __builtin_amdgcn_s_setprio(1);
#pragma unroll
        for (int s = 0; s < 2; ++s)
#pragma unroll
            for (int j = 0; j < 4; ++j) {
                short8 fK = *(const short8*)(Kq + (s * 256 + j * 64 + lane) * 8);
#pragma unroll
                for (int i = 0; i < 2; ++i)
                    sacc[i][j] = __builtin_amdgcn_mfma_f32_16x16x32_bf16(fQ[i][s], fK, sacc[i][j], 0, 0, 0);
            }
        __builtin_amdgcn_s_setprio(0);

        // ---- P = exp(S*scale); l += rowsum; P -> ldsP (A-frag, swizzled) ----
#pragma unroll
        for (int i = 0; i < 2; ++i) {
            float rs[4] = {0.f, 0.f, 0.f, 0.f};
#pragma unroll
            for (int j = 0; j < 4; ++j)
#pragma unroll
                for (int r = 0; r < 4; ++r) {
                    float p = __expf(sacc[i][j][r] * 0.125f);
                    sacc[i][j][r] = p;
                    rs[r] += p;
                }
#pragma unroll
            for (int m = 1; m < 16; m <<= 1)
#pragma unroll
                for (int r = 0; r < 4; ++r) rs[r] += __shfl_xor(rs[r], m);
#pragma unroll
            for (int r = 0; r < 4; ++r) lacc[i][r] += rs[r];
#pragma unroll
            for (int j = 0; j < 4; ++j) {
                int tt = j >> 1;
                int qq = (2 * j + (c15 >> 3)) & 3;
#pragma unroll
                for (int r = 0; r < 4; ++r) {
                    int slot = (quad * 4 + r) ^ qq;
                    int unit = (w * 2 + tt) * 128 + i * 64 + qq * 16 + slot;
                    ldsP[unit * 8 + (c15 & 7)] = f2b(sacc[i][j][r]);
                }
            }
        }

        // ---- O += P V (per-wave ldsP region: no barrier needed) ----
        __builtin_amdgcn_s_setprio(1);
#pragma unroll
        for (int tt = 0; tt < 2; ++tt) {
            short8 fP[2];
#pragma unroll
            for (int i = 0; i < 2; ++i)
                fP[i] = *(const short8*)(ldsP + ((w * 2 + tt) * 128 + i * 64
                              + quad * 16 + (c15 ^ quad)) * 8);
#pragma unroll
            for (int n = 0; n < 4; ++n) {
                short8 fV = *(const short8*)(Vq + (tt * 256 + n * 64 + lane) * 8);
#pragma unroll
                for (int i = 0; i < 2; ++i)
                    oacc[i][n] = __builtin_amdgcn_mfma_f32_16x16x32_bf16(fP[i], fV, oacc[i][n], 0, 0, 0);
            }
        }
        __builtin_amdgcn_s_setprio(0);
    }

    // ---- epilogue: O / l ----
#pragma unroll
    for (int i = 0; i < 2; ++i)
#pragma unroll
        for (int r = 0; r < 4; ++r) {
            int row = qc * 128 + (w * 2 + i) * 16 + quad * 4 + r;
            float inv = 1.f / lacc[i][r];
            bf16_t* orow = o + ((size_t)b * 4096 + row) * 1024 + h * 64;
#pragma unroll
            for (int n = 0; n < 4; ++n)
                orow[n * 16 + c15] = f2b(oacc[i][n][r] * inv);
        }
}

// ---------------- layernorm (may run in-place) ----------------
__global__ __launch_bounds__(256) void ln_kernel(
    const float* x, const float* g, const float* bta,
    float* outf, bf16_t* outb) {
    int row = blockIdx.x, t = threadIdx.x;
    const float4 vv = ((const float4*)(x + (size_t)row * 1024))[t];
    float s = vv.x + vv.y + vv.z + vv.w;
    float ss = vv.x * vv.x + vv.y * vv.y + vv.z * vv.z + vv.w * vv.w;
    for (int off = 32; off > 0; off >>= 1) {
        s += __shfl_down(s, off);
        ss += __shfl_down(ss, off);
    }
    __shared__ float red[8];
    int wave = t >> 6;
    if ((t & 63) == 0) { red[wave] = s; red[wave + 4] = ss; }
    __syncthreads();
    float ts = red[0] + red[1] + red[2] + red[3];
    float tss = red[4] + red[5] + red[6] + red[7];
    float mu = ts * (1.f / 1024.f);
    float var = tss * (1.f / 1024.f) - mu * mu;
    float rstd = rsqrtf(var + 1e-6f);
    float4 gv = ((const float4*)g)[t];
    float4 bv = ((const float4*)bta)[t];
    float4 ov;
    ov.x = (vv.x - mu) * rstd * gv.x + bv.x;
    ov.y = (vv.y - mu) * rstd * gv.y + bv.y;
    ov.z = (vv.z - mu) * rstd * gv.z + bv.z;
    ov.w = (vv.w - mu) * rstd * gv.w + bv.w;
    if (outf) ((float4*)(outf + (size_t)row * 1024))[t] = ov;
    if (outb) {
        uint2 pk;
        pk.x = (unsigned)f2b(ov.x) | ((unsigned)f2b(ov.y) << 16);
        pk.y = (unsigned)f2b(ov.z) | ((unsigned)f2b(ov.w) << 16);
        ((uint2*)(outb + (size_t)row * 1024))[t] = pk;
    }
}

// ---------------- launch ----------------
extern "C" void kernel_launch(void* const* d_in, const int* in_sizes, int n_in,
                              void* d_out, int out_size, void* d_ws, size_t ws_size,
                              hipStream_t stream) {
    const float* src = (const float*)d_in[0];
    const float* Wq = (const float*)d_in[2];  const float* bq = (const float*)d_in[3];
    const float* Wk = (const float*)d_in[4];  const float* bk = (const float*)d_in[5];
    const float* Wv = (const float*)d_in[6];  const float* bv = (const float*)d_in[7];
    const float* Wo = (const float*)d_in[8];  const float* bo = (const float*)d_in[9];
    const float* g1 = (const float*)d_in[10]; const float* be1 = (const float*)d_in[11];
    const float* W1 = (const float*)d_in[12]; const float* b1 = (const float*)d_in[13];
    const float* W2 = (const float*)d_in[14]; const float* b2 = (const float*)d_in[15];
    const float* g2 = (const float*)d_in[16]; const float* be2 = (const float*)d_in[17];
    float* out = (float*)d_out;   // also the fp32 residual stream (64 MB)
    char* ws = (char*)d_ws;
    const size_t MB = 1ull << 20;

    // layout (MB), peak 172 (ws >= 176 confirmed r5):
    //  [0,32)    xb -> ob -> alnb   (sequential lifetimes)
    //  [32,128)  qkv (96) -> hb (64, chunked FFN)
    //  [128,134) wqkvt  [134,136) wot  [136,144) w1t  [144,152) w2t
    //  [152,168) vt_l (16)  [168,172) vt_g (4)
    bf16_t* xb    = (bf16_t*)(ws + 0 * MB);
    bf16_t* ob    = (bf16_t*)(ws + 0 * MB);
    bf16_t* alnb  = (bf16_t*)(ws + 0 * MB);
    bf16_t* qkv   = (bf16_t*)(ws + 32 * MB);
    bf16_t* hb    = (bf16_t*)(ws + 32 * MB);
    bf16_t* wqkvt = (bf16_t*)(ws + 128 * MB);
    bf16_t* wot   = (bf16_t*)(ws + 134 * MB);
    bf16_t* w1t   = (bf16_t*)(ws + 136 * MB);
    bf16_t* w2t   = (bf16_t*)(ws + 144 * MB);
    bf16_t* vt_l  = (bf16_t*)(ws + 152 * MB);
    bf16_t* vt_g  = (bf16_t*)(ws + 168 * MB);

    dim3 tb(32, 8);
    transpose_convert<<<dim3(32, 32), tb, 0, stream>>>(Wq, wqkvt, 1024, 1024);
    transpose_convert<<<dim3(32, 32), tb, 0, stream>>>(Wk, wqkvt + 1024 * 1024, 1024, 1024);
    transpose_convert<<<dim3(32, 32), tb, 0, stream>>>(Wv, wqkvt + 2 * 1024 * 1024, 1024, 1024);
    transpose_convert<<<dim3(32, 32), tb, 0, stream>>>(Wo, wot, 1024, 1024);
    transpose_convert<<<dim3(128, 32), tb, 0, stream>>>(W1, w1t, 1024, 4096);
    transpose_convert<<<dim3(32, 128), tb, 0, stream>>>(W2, w2t, 4096, 1024);
    f32_to_bf16_vec<<<16384, 256, 0, stream>>>(src, xb, 4194304);

    // fused QKV: C[M][3072] = xb @ [Wq|Wk|Wv]^T, per-segment bias
    gemm_bt<256><<<dim3(64, 12), 512, 0, stream>>>(xb, wqkvt, bq, bk, bv,
        nullptr, nullptr, nullptr, qkv, 3072, 1024, 0);

    // V transpose prepass (local heads 0..8 over all toks; global heads 8..16
    // over the 1024 compacted keys)
    v_transpose<false><<<dim3(64, 8, 4), 256, 0, stream>>>(qkv, vt_l, 4096);
    v_transpose<true ><<<dim3(16, 8, 4), 256, 0, stream>>>(qkv, vt_g, 1024);

    mfma_attn<2,  false><<<dim3(32, 8, 4), 256, 0, stream>>>(qkv, vt_l, ob, 0);
    mfma_attn<16, true ><<<dim3(32, 8, 4), 256, 0, stream>>>(qkv, vt_g, ob, 8);

    // out-proj + src residual -> out (fp32)
    gemm_bt<256><<<dim3(64, 4), 512, 0, stream>>>(ob, wot, bo, nullptr, nullptr,
        src, nullptr, out, nullptr, 1024, 1024, 0);
    ln_kernel<<<16384, 256, 0, stream>>>(out, g1, be1, nullptr, alnb);

    // FFN in two 8192-row chunks (hb fits in the dead qkv region)
    for (int mc = 0; mc < 2; ++mc) {
        const bf16_t* arows = alnb + (size_t)mc * 8192 * 1024;
        float* yrows = out + (size_t)mc * 8192 * 1024;
        gemm_bt<256><<<dim3(32, 16), 512, 0, stream>>>(arows, w1t, b1, nullptr, nullptr,
            nullptr, nullptr, nullptr, hb, 4096, 1024, 1);
        gemm_bt<128><<<dim3(32, 8), 512, 0, stream>>>(hb, w2t, b2, nullptr, nullptr,
            nullptr, arows, yrows, nullptr, 1024, 4096, 0);
    }
    ln_kernel<<<16384, 256, 0, stream>>>(out, g2, be2, out, nullptr);

    (void)in_sizes; (void)n_in; (void)out_size; (void)ws_size;
}

// Round 4
// 974.997 us; speedup vs baseline: 1.3692x; 1.0142x over previous
//
#include <hip/hip_runtime.h>
#include <hip/hip_bf16.h>
#include <stdint.h>

// EncoderLayer: B=4 S=4096 D=1024 H=16 HD=64 HL=8 STRIDE=128 C=32 DFF=4096
// bf16 MFMA internal compute (validated: absmax 0.031 vs 0.109 threshold).
// R10: gemm_bt K-loop gets register double-buffered fragments: iter t reads
// tile t+1's LDS fragments into the alternate named reg set (hand-2-stepped
// loop, no runtime indexing -> no scratch) and then MFMAs tile t, so the
// ds_read stream overlaps the MFMA cluster (r9 counters: MfmaUtil 29%,
// iter ~3670cyc vs 1240 MFMA floor -- read phase and MFMA phase serialized).
// vmcnt tightened to LPT (tile t+1 landed, t+2 in flight). Staging skeleton,
// attn (R8), v_transpose prepass, LN all unchanged.

typedef unsigned short bf16_t;
typedef __attribute__((ext_vector_type(8))) short short8;
typedef __attribute__((ext_vector_type(4))) float v4f;

static __device__ __forceinline__ unsigned short f2b(float f) {
    unsigned int x = __float_as_uint(f);
    x += 0x7fffu + ((x >> 16) & 1u);   // RNE
    return (unsigned short)(x >> 16);
}
static __device__ __forceinline__ float b2f(unsigned short u) {
    return __uint_as_float(((unsigned int)u) << 16);
}

// async global->LDS 16B: LDS dest is wave-uniform base + lane*16
static __device__ __forceinline__ void gload16(const void* g, void* l) {
    __builtin_amdgcn_global_load_lds(
        (const __attribute__((address_space(1))) uint32_t*)g,
        (__attribute__((address_space(3))) uint32_t*)l, 16, 0, 0);
}

template<int N>
static __device__ __forceinline__ void vmwait() {
    asm volatile("s_waitcnt vmcnt(%0)" :: "n"(N) : "memory");
}
static __device__ __forceinline__ void lgkmwait0() {
    asm volatile("s_waitcnt lgkmcnt(0)" ::: "memory");
}

// ---------------- converts ----------------

__global__ __launch_bounds__(256) void transpose_convert(
    const float* __restrict__ W, bf16_t* __restrict__ Wt, int K, int N) {
    __shared__ float tile[32][33];
    int n0 = blockIdx.x * 32, k0 = blockIdx.y * 32;
    int tx = threadIdx.x, ty = threadIdx.y;
    for (int i = ty; i < 32; i += 8)
        tile[i][tx] = W[(size_t)(k0 + i) * N + n0 + tx];
    __syncthreads();
    for (int i = ty; i < 32; i += 8)
        Wt[(size_t)(n0 + i) * K + k0 + tx] = f2b(tile[tx][i]);
}

__global__ __launch_bounds__(256) void f32_to_bf16_vec(
    const float* __restrict__ in, bf16_t* __restrict__ out, int n4) {
    int i = blockIdx.x * blockDim.x + threadIdx.x;
    if (i >= n4) return;
    float4 v = ((const float4*)in)[i];
    uint2 p;
    p.x = (unsigned)f2b(v.x) | ((unsigned)f2b(v.y) << 16);
    p.y = (unsigned)f2b(v.z) | ((unsigned)f2b(v.w) << 16);
    ((uint2*)out)[i] = p;
}

// ---------------- V transpose prepass ----------------
// Builds vt[(b*8+h)*64 + d][tok'] (bf16) from qkv's V segment, where tok' is
// the compacted key index (identity for local heads, the C=32 tail-of-stride
// gather for global heads). XOR-swizzled LDS tile (row>>3) keeps both phases
// bank-conflict-free at short8 width.
template<bool GLOBAL>
__global__ __launch_bounds__(256) void v_transpose(
    const bf16_t* __restrict__ qkv, bf16_t* __restrict__ vt, int ntok) {
    __shared__ bf16_t tile[4096];
    int tb = blockIdx.x, h = blockIdx.y, b = blockIdx.z;
    int t = threadIdx.x;
    size_t src = (size_t)b * 4096 * 3072 + (size_t)(GLOBAL ? h + 8 : h) * 64 + 2048;
    for (int u = t; u < 512; u += 256) {
        int row = u >> 3, g = u & 7;
        int lt = tb * 64 + row;
        int tok = GLOBAL ? ((lt >> 5) * 128 + 96 + (lt & 31)) : lt;
        short8 vrow = *(const short8*)(qkv + src + (size_t)tok * 3072 + g * 8);
        *(short8*)&tile[(row * 8 + (g ^ (row >> 3))) * 8] = vrow;
    }
    __syncthreads();
    for (int u = t; u < 512; u += 256) {
        int d = u >> 3, t8g = u & 7;
        short8 vcol;
#pragma unroll
        for (int j = 0; j < 8; ++j) {
            int row = t8g * 8 + j;
            vcol[j] = tile[(row * 8 + ((d >> 3) ^ (row >> 3))) * 8 + (d & 7)];
        }
        *(short8*)(vt + ((size_t)(b * 8 + h) * 64 + d) * ntok + (size_t)tb * 64 + t8g * 8) = vcol;
    }
}

// ---------------- GEMM: C[M][N] = A[M][K] @ Bt[N][K]^T + bias (+res)(+relu) ---------
// BM=256 fixed, BN template (256 or 128). BK=32. 512 threads = 8 waves (2 M x 4 N).
// 4 circular LDS K-tile buffers, counted vmcnt, raw s_barrier, setprio MFMA,
// register double-buffered fragments (read t+1 while MFMA t).
template<int BN>
__global__ __launch_bounds__(512, 2) void gemm_bt(
    const bf16_t* __restrict__ A, const bf16_t* __restrict__ Bt,
    const float* __restrict__ bias, const float* __restrict__ bias2,
    const float* __restrict__ bias3, const float* __restrict__ resf,
    const bf16_t* __restrict__ resb, float* __restrict__ Cf,
    bf16_t* __restrict__ Cb, int N, int K, int relu) {
    constexpr int N_REP = BN / 64;     // fB frags per wave
    constexpr int BLD = BN / 128;      // B staging passes (512 units each)
    constexpr int LPT = 2 + BLD;       // gload16 per thread per K-tile
    constexpr int ASH = 8192;          // A-tile shorts (256x32)
    constexpr int TSH = ASH + BN * 32; // shorts per buffer
    __shared__ bf16_t lds[4][TSH];

    int t = threadIdx.x;
    int lane = t & 63;
    int wave = t >> 6;
    int wm = (wave >> 2) * 128;
    int wn = (wave & 3) * (BN / 4);
    int m0 = blockIdx.x * 256, n0 = blockIdx.y * BN;

    size_t aoff[2]; int adst[2];
#pragma unroll
    for (int p = 0; p < 2; ++p) {
        int u = p * 512 + t;
        int row = ((u >> 6) << 4) + (lane & 15);
        int kk = ((u >> 4) & 3) * 8;
        aoff[p] = (size_t)(m0 + row) * K + kk;
        adst[p] = (u & ~63) * 8;
    }
    size_t boff[BLD]; int bdst[BLD];
#pragma unroll
    for (int p = 0; p < BLD; ++p) {
        int u = p * 512 + t;
        int row = ((u >> 6) << 4) + (lane & 15);
        int kk = ((u >> 4) & 3) * 8;
        boff[p] = (size_t)(n0 + row) * K + kk;
        bdst[p] = (u & ~63) * 8;
    }

    auto stage = [&](int buf, int kt) {
        int k0 = kt * 32;
#pragma unroll
        for (int p = 0; p < 2; ++p)
            gload16(A + aoff[p] + k0, &lds[buf][adst[p]]);
#pragma unroll
        for (int p = 0; p < BLD; ++p)
            gload16(Bt + boff[p] + k0, &lds[buf][ASH + bdst[p]]);
    };

    v4f acc[8][N_REP];
#pragma unroll
    for (int i = 0; i < 8; ++i)
#pragma unroll
        for (int j = 0; j < N_REP; ++j) acc[i][j] = {0.f, 0.f, 0.f, 0.f};

    int NT = K >> 5;
    stage(0, 0); stage(1, 1); stage(2, 2);

    int aro = (wm >> 4) * 512 + lane * 8;
    int bro = ASH + (wn >> 4) * 512 + lane * 8;

    short8 fA0[8], fB0[N_REP], fA1[8], fB1[N_REP];

    // prep(it, gA, gB): make tile it+1's fragments resident in (gA,gB) and
    // issue stage(it+3). vmwait<LPT>: own tile-(it+1) loads landed (t+2's may
    // remain); barrier makes that collective across waves. stage target
    // buf[(it+3)&3] == buf[(it-1)&3]: its readers ran >=2 barriers ago.
    auto prep = [&](int it, short8 (&gA)[8], short8 (&gB)[N_REP]) {
        if (it + 1 < NT) {
            if (it + 2 < NT) vmwait<LPT>();
            else vmwait<0>();
            __builtin_amdgcn_s_barrier();
            __builtin_amdgcn_sched_barrier(0);
            int nb = (it + 1) & 3;
#pragma unroll
            for (int i = 0; i < 8; ++i)
                gA[i] = *(const short8*)&lds[nb][aro + i * 512];
#pragma unroll
            for (int j = 0; j < N_REP; ++j)
                gB[j] = *(const short8*)&lds[nb][bro + j * 512];
            if (it + 3 < NT) stage((it + 3) & 3, it + 3);
        }
    };
    auto mstep = [&](short8 (&gA)[8], short8 (&gB)[N_REP]) {
        __builtin_amdgcn_s_setprio(1);
#pragma unroll
        for (int i = 0; i < 8; ++i)
#pragma unroll
            for (int j = 0; j < N_REP; ++j)
                acc[i][j] = __builtin_amdgcn_mfma_f32_16x16x32_bf16(gA[i], gB[j], acc[i][j], 0, 0, 0);
        __builtin_amdgcn_s_setprio(0);
    };

    // prologue: tile 0 -> set0
    vmwait<2 * LPT>();
    __builtin_amdgcn_s_barrier();
    __builtin_amdgcn_sched_barrier(0);
#pragma unroll
    for (int i = 0; i < 8; ++i) fA0[i] = *(const short8*)&lds[0][aro + i * 512];
#pragma unroll
    for (int j = 0; j < N_REP; ++j) fB0[j] = *(const short8*)&lds[0][bro + j * 512];

    // NT is even for all instances (32 or 128): hand-2-stepped loop keeps
    // fragment sets statically named (rule: no runtime-indexed reg arrays).
    for (int it = 0; it < NT; it += 2) {
        prep(it, fA1, fB1);        // tile it+1 -> set1, stage it+3
        mstep(fA0, fB0);           // MFMA tile it (overlaps set1 ds_reads)
        prep(it + 1, fA0, fB0);    // tile it+2 -> set0, stage it+4
        mstep(fA1, fB1);           // MFMA tile it+1
    }

    int qrow = (lane >> 4) * 4;
    int c15 = lane & 15;
#pragma unroll
    for (int i = 0; i < 8; ++i) {
#pragma unroll
        for (int j = 0; j < N_REP; ++j) {
            int col = n0 + wn + j * 16 + c15;
            float bval;
            if (bias2) {
                int seg = col >> 10;
                const float* bp = seg == 0 ? bias : (seg == 1 ? bias2 : bias3);
                bval = bp[col & 1023];
            } else {
                bval = bias[col];
            }
#pragma unroll
            for (int r = 0; r < 4; ++r) {
                int row = m0 + wm + i * 16 + qrow + r;
                size_t idx = (size_t)row * N + col;
                float val = acc[i][j][r] + bval;
                if (resf) val += resf[idx];
                if (resb) val += b2f(resb[idx]);
                if (relu) val = fmaxf(val, 0.f);
                if (Cf) Cf[idx] = val;
                if (Cb) Cb[idx] = f2b(val);
            }
        }
    }
}

// ---------------- MFMA flash attention, pipelined (R8) ----------------
// qkv interleaved [tok][3072]: q +0, k +1024, v +2048. vt is the prepass
// output [bh*64+d][tok'] (compacted keys). NCHUNK counts 64-key chunks.
// LDS (shorts): [0,8192) Q (preload) aliased by P (128q x 64k A-frag);
//   [8192,20480) K bufs 3 x 4096; [20480,32768) Vt bufs 3 x 4096. 64KB.
template<int NCHUNK, bool GLOBAL>
__global__ __launch_bounds__(256) void mfma_attn(
    const bf16_t* __restrict__ qkv, const bf16_t* __restrict__ vt,
    bf16_t* __restrict__ o, int head_base) {
    __shared__ bf16_t buf[32768];
    bf16_t* ldsQ = buf;
    bf16_t* ldsP = buf;
    constexpr int KB = 8192, VB = 20480;

    int qc = blockIdx.x, hh = blockIdx.y, b = blockIdx.z;
    int h = head_base + hh;
    int t = threadIdx.x, lane = t & 63, w = t >> 6;
    int quad = lane >> 4, c15 = lane & 15;
    size_t base = (size_t)b * 4096 * 3072 + (size_t)h * 64;
    const int NTOK = GLOBAL ? 1024 : 4096;
    size_t vtbase = (size_t)(b * 8 + hh) * 64 * NTOK + (GLOBAL ? 0 : (size_t)qc * 128);
    const int CADV = (GLOBAL ? 256 : 64) * 3072;   // K token advance per chunk

    size_t koff[2]; int kdst[2];
#pragma unroll
    for (int p = 0; p < 2; ++p) {
        int u = p * 256 + t;
        int s = u >> 8;
        int kl = ((u >> 6) & 3) * 16 + (lane & 15);
        int dk = s * 32 + ((lane >> 4) & 3) * 8;
        int tok0 = GLOBAL ? ((kl >> 5) * 128 + 96 + (kl & 31)) : (qc * 128 + kl);
        koff[p] = base + 1024 + (size_t)tok0 * 3072 + dk;
        kdst[p] = KB + (u & ~63) * 8;
    }
    size_t voff[2]; int vdst[2];
#pragma unroll
    for (int p = 0; p < 2; ++p) {
        int u = p * 256 + t;
        int dd = ((u >> 6) & 3) * 16 + (lane & 15);
        int kl = (u >> 8) * 32 + ((lane >> 4) & 3) * 8;
        voff[p] = vtbase + (size_t)dd * NTOK + kl;
        vdst[p] = VB + (u & ~63) * 8;
    }

    auto stage = [&](int c) {
        int q = c % 3;
        size_t ka = (size_t)c * CADV;
        size_t va = (size_t)c * 64;
#pragma unroll
        for (int p = 0; p < 2; ++p)
            gload16(qkv + koff[p] + ka, buf + kdst[p] + q * 4096);
#pragma unroll
        for (int p = 0; p < 2; ++p)
            gload16(vt + voff[p] + va, buf + vdst[p] + q * 4096);
    };

    // ---- stage Q in A-frag order ----
#pragma unroll
    for (int u = t; u < 1024; u += 256) {
        int s = u >> 9, mt = (u >> 6) & 7, qq = (u >> 4) & 3, ll = u & 15;
        int tok = qc * 128 + mt * 16 + ll;
        gload16(qkv + base + (size_t)tok * 3072 + s * 32 + qq * 8, ldsQ + (u & ~63) * 8);
    }
    stage(0);
    stage(1);
    vmwait<8>();                       // Q's 4 loads (oldest) landed, all waves
    __builtin_amdgcn_s_barrier();

    short8 fQ[2][2];
#pragma unroll
    for (int i = 0; i < 2; ++i)
#pragma unroll
        for (int s = 0; s < 2; ++s)
            fQ[i][s] = *(const short8*)(ldsQ + (s * 512 + (w * 2 + i) * 64 + lane) * 8);
    lgkmwait0();                       // fQ in regs before P region gets written
    __builtin_amdgcn_sched_barrier(0);

    v4f oacc[2][4];
    float lacc[2][4];
#pragma unroll
    for (int i = 0; i < 2; ++i)
#pragma unroll
        for (int n = 0; n < 4; ++n) oacc[i][n] = {0.f, 0.f, 0.f, 0.f};
#pragma unroll
    for (int i = 0; i < 2; ++i)
#pragma unroll
        for (int r = 0; r < 4; ++r) lacc[i][r] = 0.f;

    for (int c = 0; c < NCHUNK; ++c) {
        if (c + 1 < NCHUNK) vmwait<4>();
        else vmwait<0>();
        __builtin_amdgcn_s_barrier();
        __builtin_amdgcn_sched_barrier(0);
        if (c + 2 < NCHUNK) stage(c + 2);

        const bf16_t* Kq = buf + KB + (c % 3) * 4096;
        const bf16_t* Vq = buf + VB + (c % 3) * 4096;

        // ---- S = Q K^T ----
        v4f sacc[2][4];
#pragma unroll
        for (int i = 0; i < 2; ++i)
#pragma unroll
            for (int j = 0; j < 4; ++j) sacc[i][j] = {0.f, 0.f, 0.f, 0.f};
        __builtin_amdgcn_s_setprio(1);
#pragma unroll
        for (int s = 0; s < 2; ++s)
#pragma unroll
            for (int j = 0; j < 4; ++j) {
                short8 fK = *(const short8*)(Kq + (s * 256 + j * 64 + lane) * 8);
#pragma unroll
                for (int i = 0; i < 2; ++i)
                    sacc[i][j] = __builtin_amdgcn_mfma_f32_16x16x32_bf16(fQ[i][s], fK, sacc[i][j], 0, 0, 0);
            }
        __builtin_amdgcn_s_setprio(0);

        // ---- P = exp(S*scale); l += rowsum; P -> ldsP (A-frag, swizzled) ----
#pragma unroll
        for (int i = 0; i < 2; ++i) {
            float rs[4] = {0.f, 0.f, 0.f, 0.f};
#pragma unroll
            for (int j = 0; j < 4; ++j)
#pragma unroll
                for (int r = 0; r < 4; ++r) {
                    float p = __expf(sacc[i][j][r] * 0.125f);
                    sacc[i][j][r] = p;
                    rs[r] += p;
                }
#pragma unroll
            for (int m = 1; m < 16; m <<= 1)
#pragma unroll
                for (int r = 0; r < 4; ++r) rs[r] += __shfl_xor(rs[r], m);
#pragma unroll
            for (int r = 0; r < 4; ++r) lacc[i][r] += rs[r];
#pragma unroll
            for (int j = 0; j < 4; ++j) {
                int tt = j >> 1;
                int qq = (2 * j + (c15 >> 3)) & 3;
#pragma unroll
                for (int r = 0; r < 4; ++r) {
                    int slot = (quad * 4 + r) ^ qq;
                    int unit = (w * 2 + tt) * 128 + i * 64 + qq * 16 + slot;
                    ldsP[unit * 8 + (c15 & 7)] = f2b(sacc[i][j][r]);
                }
            }
        }

        // ---- O += P V (per-wave ldsP region: no barrier needed) ----
        __builtin_amdgcn_s_setprio(1);
#pragma unroll
        for (int tt = 0; tt < 2; ++tt) {
            short8 fP[2];
#pragma unroll
            for (int i = 0; i < 2; ++i)
                fP[i] = *(const short8*)(ldsP + ((w * 2 + tt) * 128 + i * 64
                              + quad * 16 + (c15 ^ quad)) * 8);
#pragma unroll
            for (int n = 0; n < 4; ++n) {
                short8 fV = *(const short8*)(Vq + (tt * 256 + n * 64 + lane) * 8);
#pragma unroll
                for (int i = 0; i < 2; ++i)
                    oacc[i][n] = __builtin_amdgcn_mfma_f32_16x16x32_bf16(fP[i], fV, oacc[i][n], 0, 0, 0);
            }
        }
        __builtin_amdgcn_s_setprio(0);
    }

    // ---- epilogue: O / l ----
#pragma unroll
    for (int i = 0; i < 2; ++i)
#pragma unroll
        for (int r = 0; r < 4; ++r) {
            int row = qc * 128 + (w * 2 + i) * 16 + quad * 4 + r;
            float inv = 1.f / lacc[i][r];
            bf16_t* orow = o + ((size_t)b * 4096 + row) * 1024 + h * 64;
#pragma unroll
            for (int n = 0; n < 4; ++n)
                orow[n * 16 + c15] = f2b(oacc[i][n][r] * inv);
        }
}

// ---------------- layernorm (may run in-place) ----------------
__global__ __launch_bounds__(256) void ln_kernel(
    const float* x, const float* g, const float* bta,
    float* outf, bf16_t* outb) {
    int row = blockIdx.x, t = threadIdx.x;
    const float4 vv = ((const float4*)(x + (size_t)row * 1024))[t];
    float s = vv.x + vv.y + vv.z + vv.w;
    float ss = vv.x * vv.x + vv.y * vv.y + vv.z * vv.z + vv.w * vv.w;
    for (int off = 32; off > 0; off >>= 1) {
        s += __shfl_down(s, off);
        ss += __shfl_down(ss, off);
    }
    __shared__ float red[8];
    int wave = t >> 6;
    if ((t & 63) == 0) { red[wave] = s; red[wave + 4] = ss; }
    __syncthreads();
    float ts = red[0] + red[1] + red[2] + red[3];
    float tss = red[4] + red[5] + red[6] + red[7];
    float mu = ts * (1.f / 1024.f);
    float var = tss * (1.f / 1024.f) - mu * mu;
    float rstd = rsqrtf(var + 1e-6f);
    float4 gv = ((const float4*)g)[t];
    float4 bv = ((const float4*)bta)[t];
    float4 ov;
    ov.x = (vv.x - mu) * rstd * gv.x + bv.x;
    ov.y = (vv.y - mu) * rstd * gv.y + bv.y;
    ov.z = (vv.z - mu) * rstd * gv.z + bv.z;
    ov.w = (vv.w - mu) * rstd * gv.w + bv.w;
    if (outf) ((float4*)(outf + (size_t)row * 1024))[t] = ov;
    if (outb) {
        uint2 pk;
        pk.x = (unsigned)f2b(ov.x) | ((unsigned)f2b(ov.y) << 16);
        pk.y = (unsigned)f2b(ov.z) | ((unsigned)f2b(ov.w) << 16);
        ((uint2*)(outb + (size_t)row * 1024))[t] = pk;
    }
}

// ---------------- launch ----------------
extern "C" void kernel_launch(void* const* d_in, const int* in_sizes, int n_in,
                              void* d_out, int out_size, void* d_ws, size_t ws_size,
                              hipStream_t stream) {
    const float* src = (const float*)d_in[0];
    const float* Wq = (const float*)d_in[2];  const float* bq = (const float*)d_in[3];
    const float* Wk = (const float*)d_in[4];  const float* bk = (const float*)d_in[5];
    const float* Wv = (const float*)d_in[6];  const float* bv = (const float*)d_in[7];
    const float* Wo = (const float*)d_in[8];  const float* bo = (const float*)d_in[9];
    const float* g1 = (const float*)d_in[10]; const float* be1 = (const float*)d_in[11];
    const float* W1 = (const float*)d_in[12]; const float* b1 = (const float*)d_in[13];
    const float* W2 = (const float*)d_in[14]; const float* b2 = (const float*)d_in[15];
    const float* g2 = (const float*)d_in[16]; const float* be2 = (const float*)d_in[17];
    float* out = (float*)d_out;   // also the fp32 residual stream (64 MB)
    char* ws = (char*)d_ws;
    const size_t MB = 1ull << 20;

    // layout (MB), peak 172 (ws >= 176 confirmed r5):
    //  [0,32)    xb -> ob -> alnb   (sequential lifetimes)
    //  [32,128)  qkv (96) -> hb (64, chunked FFN)
    //  [128,134) wqkvt  [134,136) wot  [136,144) w1t  [144,152) w2t
    //  [152,168) vt_l (16)  [168,172) vt_g (4)
    bf16_t* xb    = (bf16_t*)(ws + 0 * MB);
    bf16_t* ob    = (bf16_t*)(ws + 0 * MB);
    bf16_t* alnb  = (bf16_t*)(ws + 0 * MB);
    bf16_t* qkv   = (bf16_t*)(ws + 32 * MB);
    bf16_t* hb    = (bf16_t*)(ws + 32 * MB);
    bf16_t* wqkvt = (bf16_t*)(ws + 128 * MB);
    bf16_t* wot   = (bf16_t*)(ws + 134 * MB);
    bf16_t* w1t   = (bf16_t*)(ws + 136 * MB);
    bf16_t* w2t   = (bf16_t*)(ws + 144 * MB);
    bf16_t* vt_l  = (bf16_t*)(ws + 152 * MB);
    bf16_t* vt_g  = (bf16_t*)(ws + 168 * MB);

    dim3 tb(32, 8);
    transpose_convert<<<dim3(32, 32), tb, 0, stream>>>(Wq, wqkvt, 1024, 1024);
    transpose_convert<<<dim3(32, 32), tb, 0, stream>>>(Wk, wqkvt + 1024 * 1024, 1024, 1024);
    transpose_convert<<<dim3(32, 32), tb, 0, stream>>>(Wv, wqkvt + 2 * 1024 * 1024, 1024, 1024);
    transpose_convert<<<dim3(32, 32), tb, 0, stream>>>(Wo, wot, 1024, 1024);
    transpose_convert<<<dim3(128, 32), tb, 0, stream>>>(W1, w1t, 1024, 4096);
    transpose_convert<<<dim3(32, 128), tb, 0, stream>>>(W2, w2t, 4096, 1024);
    f32_to_bf16_vec<<<16384, 256, 0, stream>>>(src, xb, 4194304);

    // fused QKV: C[M][3072] = xb @ [Wq|Wk|Wv]^T, per-segment bias
    gemm_bt<256><<<dim3(64, 12), 512, 0, stream>>>(xb, wqkvt, bq, bk, bv,
        nullptr, nullptr, nullptr, qkv, 3072, 1024, 0);

    // V transpose prepass (local heads 0..8 over all toks; global heads 8..16
    // over the 1024 compacted keys)
    v_transpose<false><<<dim3(64, 8, 4), 256, 0, stream>>>(qkv, vt_l, 4096);
    v_transpose<true ><<<dim3(16, 8, 4), 256, 0, stream>>>(qkv, vt_g, 1024);

    mfma_attn<2,  false><<<dim3(32, 8, 4), 256, 0, stream>>>(qkv, vt_l, ob, 0);
    mfma_attn<16, true ><<<dim3(32, 8, 4), 256, 0, stream>>>(qkv, vt_g, ob, 8);

    // out-proj + src residual -> out (fp32)
    gemm_bt<256><<<dim3(64, 4), 512, 0, stream>>>(ob, wot, bo, nullptr, nullptr,
        src, nullptr, out, nullptr, 1024, 1024, 0);
    ln_kernel<<<16384, 256, 0, stream>>>(out, g1, be1, nullptr, alnb);

    // FFN in two 8192-row chunks (hb fits in the dead qkv region)
    for (int mc = 0; mc < 2; ++mc) {
        const bf16_t* arows = alnb + (size_t)mc * 8192 * 1024;
        float* yrows = out + (size_t)mc * 8192 * 1024;
        gemm_bt<256><<<dim3(32, 16), 512, 0, stream>>>(arows, w1t, b1, nullptr, nullptr,
            nullptr, nullptr, nullptr, hb, 4096, 1024, 1);
        gemm_bt<128><<<dim3(32, 8), 512, 0, stream>>>(hb, w2t, b2, nullptr, nullptr,
            nullptr, arows, yrows, nullptr, 1024, 4096, 0);
    }
    ln_kernel<<<16384, 256, 0, stream>>>(out, g2, be2, out, nullptr);

    (void)in_sizes; (void)n_in; (void)out_size; (void)ws_size;
}

// Round 5
// 933.260 us; speedup vs baseline: 1.4305x; 1.0447x over previous
//
#include <hip/hip_runtime.h>
#include <hip/hip_bf16.h>
#include <stdint.h>

// EncoderLayer: B=4 S=4096 D=1024 H=16 HD=64 HL=8 STRIDE=128 C=32 DFF=4096
// bf16 MFMA internal compute (validated: absmax 0.031 vs 0.109 threshold).
// R11: (a) sched_barrier(0) BETWEEN prefetch (ds_reads+stage) and MFMA
// cluster in gemm_bt -- R10's reg-dbuf was neutral (145us, MfmaUtil 29.6
// unchanged, VGPR only 124): hypothesis = pressure-aware scheduler SANK the
// next-tile ds_reads below the MFMA cluster (saves 48 live VGPRs),
// re-serializing exactly like R9. The fence pins loads-first.
// (b) FFN unchunked: weights moved to [152,176), vt to [128,148), freeing
// [32,160) = 128MB for full hb. FFN1 = one M=16384 dispatch; FFN2 = BN=256
// grid 64x4 = 256 blocks = exactly 1 pass (was BN=128, 2 chunks x 128
// overhead-dominated K-windows ~ 320us by cycle model).

typedef unsigned short bf16_t;
typedef __attribute__((ext_vector_type(8))) short short8;
typedef __attribute__((ext_vector_type(4))) float v4f;

static __device__ __forceinline__ unsigned short f2b(float f) {
    unsigned int x = __float_as_uint(f);
    x += 0x7fffu + ((x >> 16) & 1u);   // RNE
    return (unsigned short)(x >> 16);
}
static __device__ __forceinline__ float b2f(unsigned short u) {
    return __uint_as_float(((unsigned int)u) << 16);
}

// async global->LDS 16B: LDS dest is wave-uniform base + lane*16
static __device__ __forceinline__ void gload16(const void* g, void* l) {
    __builtin_amdgcn_global_load_lds(
        (const __attribute__((address_space(1))) uint32_t*)g,
        (__attribute__((address_space(3))) uint32_t*)l, 16, 0, 0);
}

template<int N>
static __device__ __forceinline__ void vmwait() {
    asm volatile("s_waitcnt vmcnt(%0)" :: "n"(N) : "memory");
}
static __device__ __forceinline__ void lgkmwait0() {
    asm volatile("s_waitcnt lgkmcnt(0)" ::: "memory");
}

// ---------------- converts ----------------

__global__ __launch_bounds__(256) void transpose_convert(
    const float* __restrict__ W, bf16_t* __restrict__ Wt, int K, int N) {
    __shared__ float tile[32][33];
    int n0 = blockIdx.x * 32, k0 = blockIdx.y * 32;
    int tx = threadIdx.x, ty = threadIdx.y;
    for (int i = ty; i < 32; i += 8)
        tile[i][tx] = W[(size_t)(k0 + i) * N + n0 + tx];
    __syncthreads();
    for (int i = ty; i < 32; i += 8)
        Wt[(size_t)(n0 + i) * K + k0 + tx] = f2b(tile[tx][i]);
}

__global__ __launch_bounds__(256) void f32_to_bf16_vec(
    const float* __restrict__ in, bf16_t* __restrict__ out, int n4) {
    int i = blockIdx.x * blockDim.x + threadIdx.x;
    if (i >= n4) return;
    float4 v = ((const float4*)in)[i];
    uint2 p;
    p.x = (unsigned)f2b(v.x) | ((unsigned)f2b(v.y) << 16);
    p.y = (unsigned)f2b(v.z) | ((unsigned)f2b(v.w) << 16);
    ((uint2*)out)[i] = p;
}

// ---------------- V transpose prepass ----------------
// Builds vt[(b*8+h)*64 + d][tok'] (bf16) from qkv's V segment, where tok' is
// the compacted key index (identity for local heads, the C=32 tail-of-stride
// gather for global heads). XOR-swizzled LDS tile (row>>3) keeps both phases
// bank-conflict-free at short8 width.
template<bool GLOBAL>
__global__ __launch_bounds__(256) void v_transpose(
    const bf16_t* __restrict__ qkv, bf16_t* __restrict__ vt, int ntok) {
    __shared__ bf16_t tile[4096];
    int tb = blockIdx.x, h = blockIdx.y, b = blockIdx.z;
    int t = threadIdx.x;
    size_t src = (size_t)b * 4096 * 3072 + (size_t)(GLOBAL ? h + 8 : h) * 64 + 2048;
    for (int u = t; u < 512; u += 256) {
        int row = u >> 3, g = u & 7;
        int lt = tb * 64 + row;
        int tok = GLOBAL ? ((lt >> 5) * 128 + 96 + (lt & 31)) : lt;
        short8 vrow = *(const short8*)(qkv + src + (size_t)tok * 3072 + g * 8);
        *(short8*)&tile[(row * 8 + (g ^ (row >> 3))) * 8] = vrow;
    }
    __syncthreads();
    for (int u = t; u < 512; u += 256) {
        int d = u >> 3, t8g = u & 7;
        short8 vcol;
#pragma unroll
        for (int j = 0; j < 8; ++j) {
            int row = t8g * 8 + j;
            vcol[j] = tile[(row * 8 + ((d >> 3) ^ (row >> 3))) * 8 + (d & 7)];
        }
        *(short8*)(vt + ((size_t)(b * 8 + h) * 64 + d) * ntok + (size_t)tb * 64 + t8g * 8) = vcol;
    }
}

// ---------------- GEMM: C[M][N] = A[M][K] @ Bt[N][K]^T + bias (+res)(+relu) ---------
// BM=256 fixed, BN template (256 or 128). BK=32. 512 threads = 8 waves (2 M x 4 N).
// 4 circular LDS K-tile buffers, counted vmcnt, raw s_barrier, setprio MFMA,
// register double-buffered fragments (read t+1 while MFMA t), with a
// sched_barrier fence pinning the prefetch ABOVE the MFMA cluster.
template<int BN>
__global__ __launch_bounds__(512, 2) void gemm_bt(
    const bf16_t* __restrict__ A, const bf16_t* __restrict__ Bt,
    const float* __restrict__ bias, const float* __restrict__ bias2,
    const float* __restrict__ bias3, const float* __restrict__ resf,
    const bf16_t* __restrict__ resb, float* __restrict__ Cf,
    bf16_t* __restrict__ Cb, int N, int K, int relu) {
    constexpr int N_REP = BN / 64;     // fB frags per wave
    constexpr int BLD = BN / 128;      // B staging passes (512 units each)
    constexpr int LPT = 2 + BLD;       // gload16 per thread per K-tile
    constexpr int ASH = 8192;          // A-tile shorts (256x32)
    constexpr int TSH = ASH + BN * 32; // shorts per buffer
    __shared__ bf16_t lds[4][TSH];

    int t = threadIdx.x;
    int lane = t & 63;
    int wave = t >> 6;
    int wm = (wave >> 2) * 128;
    int wn = (wave & 3) * (BN / 4);
    int m0 = blockIdx.x * 256, n0 = blockIdx.y * BN;

    size_t aoff[2]; int adst[2];
#pragma unroll
    for (int p = 0; p < 2; ++p) {
        int u = p * 512 + t;
        int row = ((u >> 6) << 4) + (lane & 15);
        int kk = ((u >> 4) & 3) * 8;
        aoff[p] = (size_t)(m0 + row) * K + kk;
        adst[p] = (u & ~63) * 8;
    }
    size_t boff[BLD]; int bdst[BLD];
#pragma unroll
    for (int p = 0; p < BLD; ++p) {
        int u = p * 512 + t;
        int row = ((u >> 6) << 4) + (lane & 15);
        int kk = ((u >> 4) & 3) * 8;
        boff[p] = (size_t)(n0 + row) * K + kk;
        bdst[p] = (u & ~63) * 8;
    }

    auto stage = [&](int buf, int kt) {
        int k0 = kt * 32;
#pragma unroll
        for (int p = 0; p < 2; ++p)
            gload16(A + aoff[p] + k0, &lds[buf][adst[p]]);
#pragma unroll
        for (int p = 0; p < BLD; ++p)
            gload16(Bt + boff[p] + k0, &lds[buf][ASH + bdst[p]]);
    };

    v4f acc[8][N_REP];
#pragma unroll
    for (int i = 0; i < 8; ++i)
#pragma unroll
        for (int j = 0; j < N_REP; ++j) acc[i][j] = {0.f, 0.f, 0.f, 0.f};

    int NT = K >> 5;
    stage(0, 0); stage(1, 1); stage(2, 2);

    int aro = (wm >> 4) * 512 + lane * 8;
    int bro = ASH + (wn >> 4) * 512 + lane * 8;

    short8 fA0[8], fB0[N_REP], fA1[8], fB1[N_REP];

    // prep(it, gA, gB): make tile it+1's fragments resident in (gA,gB) and
    // issue stage(it+3). vmwait<LPT>: own tile-(it+1) loads landed (t+2's may
    // remain); barrier makes that collective across waves. stage target
    // buf[(it+3)&3] == buf[(it-1)&3]: its readers ran >=2 barriers ago.
    // Trailing sched_barrier(0): forbid the register-pressure scheduler from
    // SINKING these ds_reads/gloads below the MFMA cluster (R10 null result).
    auto prep = [&](int it, short8 (&gA)[8], short8 (&gB)[N_REP]) {
        if (it + 1 < NT) {
            if (it + 2 < NT) vmwait<LPT>();
            else vmwait<0>();
            __builtin_amdgcn_s_barrier();
            __builtin_amdgcn_sched_barrier(0);
            int nb = (it + 1) & 3;
#pragma unroll
            for (int i = 0; i < 8; ++i)
                gA[i] = *(const short8*)&lds[nb][aro + i * 512];
#pragma unroll
            for (int j = 0; j < N_REP; ++j)
                gB[j] = *(const short8*)&lds[nb][bro + j * 512];
            if (it + 3 < NT) stage((it + 3) & 3, it + 3);
            __builtin_amdgcn_sched_barrier(0);   // pin prefetch above MFMAs
        }
    };
    auto mstep = [&](short8 (&gA)[8], short8 (&gB)[N_REP]) {
        __builtin_amdgcn_s_setprio(1);
#pragma unroll
        for (int i = 0; i < 8; ++i)
#pragma unroll
            for (int j = 0; j < N_REP; ++j)
                acc[i][j] = __builtin_amdgcn_mfma_f32_16x16x32_bf16(gA[i], gB[j], acc[i][j], 0, 0, 0);
        __builtin_amdgcn_s_setprio(0);
    };

    // prologue: tile 0 -> set0
    vmwait<2 * LPT>();
    __builtin_amdgcn_s_barrier();
    __builtin_amdgcn_sched_barrier(0);
#pragma unroll
    for (int i = 0; i < 8; ++i) fA0[i] = *(const short8*)&lds[0][aro + i * 512];
#pragma unroll
    for (int j = 0; j < N_REP; ++j) fB0[j] = *(const short8*)&lds[0][bro + j * 512];

    // NT is even for all instances (32 or 128): hand-2-stepped loop keeps
    // fragment sets statically named (rule: no runtime-indexed reg arrays).
    for (int it = 0; it < NT; it += 2) {
        prep(it, fA1, fB1);        // tile it+1 -> set1, stage it+3
        mstep(fA0, fB0);           // MFMA tile it (overlaps set1 ds_reads)
        prep(it + 1, fA0, fB0);    // tile it+2 -> set0, stage it+4
        mstep(fA1, fB1);           // MFMA tile it+1
    }

    int qrow = (lane >> 4) * 4;
    int c15 = lane & 15;
#pragma unroll
    for (int i = 0; i < 8; ++i) {
#pragma unroll
        for (int j = 0; j < N_REP; ++j) {
            int col = n0 + wn + j * 16 + c15;
            float bval;
            if (bias2) {
                int seg = col >> 10;
                const float* bp = seg == 0 ? bias : (seg == 1 ? bias2 : bias3);
                bval = bp[col & 1023];
            } else {
                bval = bias[col];
            }
#pragma unroll
            for (int r = 0; r < 4; ++r) {
                int row = m0 + wm + i * 16 + qrow + r;
                size_t idx = (size_t)row * N + col;
                float val = acc[i][j][r] + bval;
                if (resf) val += resf[idx];
                if (resb) val += b2f(resb[idx]);
                if (relu) val = fmaxf(val, 0.f);
                if (Cf) Cf[idx] = val;
                if (Cb) Cb[idx] = f2b(val);
            }
        }
    }
}

// ---------------- MFMA flash attention, pipelined (R8) ----------------
// qkv interleaved [tok][3072]: q +0, k +1024, v +2048. vt is the prepass
// output [bh*64+d][tok'] (compacted keys). NCHUNK counts 64-key chunks.
// LDS (shorts): [0,8192) Q (preload) aliased by P (128q x 64k A-frag);
//   [8192,20480) K bufs 3 x 4096; [20480,32768) Vt bufs 3 x 4096. 64KB.
template<int NCHUNK, bool GLOBAL>
__global__ __launch_bounds__(256) void mfma_attn(
    const bf16_t* __restrict__ qkv, const bf16_t* __restrict__ vt,
    bf16_t* __restrict__ o, int head_base) {
    __shared__ bf16_t buf[32768];
    bf16_t* ldsQ = buf;
    bf16_t* ldsP = buf;
    constexpr int KB = 8192, VB = 20480;

    int qc = blockIdx.x, hh = blockIdx.y, b = blockIdx.z;
    int h = head_base + hh;
    int t = threadIdx.x, lane = t & 63, w = t >> 6;
    int quad = lane >> 4, c15 = lane & 15;
    size_t base = (size_t)b * 4096 * 3072 + (size_t)h * 64;
    const int NTOK = GLOBAL ? 1024 : 4096;
    size_t vtbase = (size_t)(b * 8 + hh) * 64 * NTOK + (GLOBAL ? 0 : (size_t)qc * 128);
    const int CADV = (GLOBAL ? 256 : 64) * 3072;   // K token advance per chunk

    size_t koff[2]; int kdst[2];
#pragma unroll
    for (int p = 0; p < 2; ++p) {
        int u = p * 256 + t;
        int s = u >> 8;
        int kl = ((u >> 6) & 3) * 16 + (lane & 15);
        int dk = s * 32 + ((lane >> 4) & 3) * 8;
        int tok0 = GLOBAL ? ((kl >> 5) * 128 + 96 + (kl & 31)) : (qc * 128 + kl);
        koff[p] = base + 1024 + (size_t)tok0 * 3072 + dk;
        kdst[p] = KB + (u & ~63) * 8;
    }
    size_t voff[2]; int vdst[2];
#pragma unroll
    for (int p = 0; p < 2; ++p) {
        int u = p * 256 + t;
        int dd = ((u >> 6) & 3) * 16 + (lane & 15);
        int kl = (u >> 8) * 32 + ((lane >> 4) & 3) * 8;
        voff[p] = vtbase + (size_t)dd * NTOK + kl;
        vdst[p] = VB + (u & ~63) * 8;
    }

    auto stage = [&](int c) {
        int q = c % 3;
        size_t ka = (size_t)c * CADV;
        size_t va = (size_t)c * 64;
#pragma unroll
        for (int p = 0; p < 2; ++p)
            gload16(qkv + koff[p] + ka, buf + kdst[p] + q * 4096);
#pragma unroll
        for (int p = 0; p < 2; ++p)
            gload16(vt + voff[p] + va, buf + vdst[p] + q * 4096);
    };

    // ---- stage Q in A-frag order ----
#pragma unroll
    for (int u = t; u < 1024; u += 256) {
        int s = u >> 9, mt = (u >> 6) & 7, qq = (u >> 4) & 3, ll = u & 15;
        int tok = qc * 128 + mt * 16 + ll;
        gload16(qkv + base + (size_t)tok * 3072 + s * 32 + qq * 8, ldsQ + (u & ~63) * 8);
    }
    stage(0);
    stage(1);
    vmwait<8>();                       // Q's 4 loads (oldest) landed, all waves
    __builtin_amdgcn_s_barrier();

    short8 fQ[2][2];
#pragma unroll
    for (int i = 0; i < 2; ++i)
#pragma unroll
        for (int s = 0; s < 2; ++s)
            fQ[i][s] = *(const short8*)(ldsQ + (s * 512 + (w * 2 + i) * 64 + lane) * 8);
    lgkmwait0();                       // fQ in regs before P region gets written
    __builtin_amdgcn_sched_barrier(0);

    v4f oacc[2][4];
    float lacc[2][4];
#pragma unroll
    for (int i = 0; i < 2; ++i)
#pragma unroll
        for (int n = 0; n < 4; ++n) oacc[i][n] = {0.f, 0.f, 0.f, 0.f};
#pragma unroll
    for (int i = 0; i < 2; ++i)
#pragma unroll
        for (int r = 0; r < 4; ++r) lacc[i][r] = 0.f;

    for (int c = 0; c < NCHUNK; ++c) {
        if (c + 1 < NCHUNK) vmwait<4>();
        else vmwait<0>();
        __builtin_amdgcn_s_barrier();
        __builtin_amdgcn_sched_barrier(0);
        if (c + 2 < NCHUNK) stage(c + 2);

        const bf16_t* Kq = buf + KB + (c % 3) * 4096;
        const bf16_t* Vq = buf + VB + (c % 3) * 4096;

        // ---- S = Q K^T ----
        v4f sacc[2][4];
#pragma unroll
        for (int i = 0; i < 2; ++i)
#pragma unroll
            for (int j = 0; j < 4; ++j) sacc[i][j] = {0.f, 0.f, 0.f, 0.f};
        __builtin_amdgcn_s_setprio(1);
#pragma unroll
        for (int s = 0; s < 2; ++s)
#pragma unroll
            for (int j = 0; j < 4; ++j) {
                short8 fK = *(const short8*)(Kq + (s * 256 + j * 64 + lane) * 8);
#pragma unroll
                for (int i = 0; i < 2; ++i)
                    sacc[i][j] = __builtin_amdgcn_mfma_f32_16x16x32_bf16(fQ[i][s], fK, sacc[i][j], 0, 0, 0);
            }
        __builtin_amdgcn_s_setprio(0);

        // ---- P = exp(S*scale); l += rowsum; P -> ldsP (A-frag, swizzled) ----
#pragma unroll
        for (int i = 0; i < 2; ++i) {
            float rs[4] = {0.f, 0.f, 0.f, 0.f};
#pragma unroll
            for (int j = 0; j < 4; ++j)
#pragma unroll
                for (int r = 0; r < 4; ++r) {
                    float p = __expf(sacc[i][j][r] * 0.125f);
                    sacc[i][j][r] = p;
                    rs[r] += p;
                }
#pragma unroll
            for (int m = 1; m < 16; m <<= 1)
#pragma unroll
                for (int r = 0; r < 4; ++r) rs[r] += __shfl_xor(rs[r], m);
#pragma unroll
            for (int r = 0; r < 4; ++r) lacc[i][r] += rs[r];
#pragma unroll
            for (int j = 0; j < 4; ++j) {
                int tt = j >> 1;
                int qq = (2 * j + (c15 >> 3)) & 3;
#pragma unroll
                for (int r = 0; r < 4; ++r) {
                    int slot = (quad * 4 + r) ^ qq;
                    int unit = (w * 2 + tt) * 128 + i * 64 + qq * 16 + slot;
                    ldsP[unit * 8 + (c15 & 7)] = f2b(sacc[i][j][r]);
                }
            }
        }

        // ---- O += P V (per-wave ldsP region: no barrier needed) ----
        __builtin_amdgcn_s_setprio(1);
#pragma unroll
        for (int tt = 0; tt < 2; ++tt) {
            short8 fP[2];
#pragma unroll
            for (int i = 0; i < 2; ++i)
                fP[i] = *(const short8*)(ldsP + ((w * 2 + tt) * 128 + i * 64
                              + quad * 16 + (c15 ^ quad)) * 8);
#pragma unroll
            for (int n = 0; n < 4; ++n) {
                short8 fV = *(const short8*)(Vq + (tt * 256 + n * 64 + lane) * 8);
#pragma unroll
                for (int i = 0; i < 2; ++i)
                    oacc[i][n] = __builtin_amdgcn_mfma_f32_16x16x32_bf16(fP[i], fV, oacc[i][n], 0, 0, 0);
            }
        }
        __builtin_amdgcn_s_setprio(0);
    }

    // ---- epilogue: O / l ----
#pragma unroll
    for (int i = 0; i < 2; ++i)
#pragma unroll
        for (int r = 0; r < 4; ++r) {
            int row = qc * 128 + (w * 2 + i) * 16 + quad * 4 + r;
            float inv = 1.f / lacc[i][r];
            bf16_t* orow = o + ((size_t)b * 4096 + row) * 1024 + h * 64;
#pragma unroll
            for (int n = 0; n < 4; ++n)
                orow[n * 16 + c15] = f2b(oacc[i][n][r] * inv);
        }
}

// ---------------- layernorm (may run in-place) ----------------
__global__ __launch_bounds__(256) void ln_kernel(
    const float* x, const float* g, const float* bta,
    float* outf, bf16_t* outb) {
    int row = blockIdx.x, t = threadIdx.x;
    const float4 vv = ((const float4*)(x + (size_t)row * 1024))[t];
    float s = vv.x + vv.y + vv.z + vv.w;
    float ss = vv.x * vv.x + vv.y * vv.y + vv.z * vv.z + vv.w * vv.w;
    for (int off = 32; off > 0; off >>= 1) {
        s += __shfl_down(s, off);
        ss += __shfl_down(ss, off);
    }
    __shared__ float red[8];
    int wave = t >> 6;
    if ((t & 63) == 0) { red[wave] = s; red[wave + 4] = ss; }
    __syncthreads();
    float ts = red[0] + red[1] + red[2] + red[3];
    float tss = red[4] + red[5] + red[6] + red[7];
    float mu = ts * (1.f / 1024.f);
    float var = tss * (1.f / 1024.f) - mu * mu;
    float rstd = rsqrtf(var + 1e-6f);
    float4 gv = ((const float4*)g)[t];
    float4 bv = ((const float4*)bta)[t];
    float4 ov;
    ov.x = (vv.x - mu) * rstd * gv.x + bv.x;
    ov.y = (vv.y - mu) * rstd * gv.y + bv.y;
    ov.z = (vv.z - mu) * rstd * gv.z + bv.z;
    ov.w = (vv.w - mu) * rstd * gv.w + bv.w;
    if (outf) ((float4*)(outf + (size_t)row * 1024))[t] = ov;
    if (outb) {
        uint2 pk;
        pk.x = (unsigned)f2b(ov.x) | ((unsigned)f2b(ov.y) << 16);
        pk.y = (unsigned)f2b(ov.z) | ((unsigned)f2b(ov.w) << 16);
        ((uint2*)(outb + (size_t)row * 1024))[t] = pk;
    }
}

// ---------------- launch ----------------
extern "C" void kernel_launch(void* const* d_in, const int* in_sizes, int n_in,
                              void* d_out, int out_size, void* d_ws, size_t ws_size,
                              hipStream_t stream) {
    const float* src = (const float*)d_in[0];
    const float* Wq = (const float*)d_in[2];  const float* bq = (const float*)d_in[3];
    const float* Wk = (const float*)d_in[4];  const float* bk = (const float*)d_in[5];
    const float* Wv = (const float*)d_in[6];  const float* bv = (const float*)d_in[7];
    const float* Wo = (const float*)d_in[8];  const float* bo = (const float*)d_in[9];
    const float* g1 = (const float*)d_in[10]; const float* be1 = (const float*)d_in[11];
    const float* W1 = (const float*)d_in[12]; const float* b1 = (const float*)d_in[13];
    const float* W2 = (const float*)d_in[14]; const float* b2 = (const float*)d_in[15];
    const float* g2 = (const float*)d_in[16]; const float* be2 = (const float*)d_in[17];
    float* out = (float*)d_out;   // also the fp32 residual stream (64 MB)
    char* ws = (char*)d_ws;
    const size_t MB = 1ull << 20;

    // layout (MB), ws >= 176 confirmed r5. Lifetimes:
    //  [0,32)    xb -> ob -> alnb          (sequential)
    //  [32,128)  qkv (96)                  (dead after attn)
    //  [128,144) vt_l  [144,148) vt_g      (dead after attn)
    //  [152,158) wqkvt (dead after QKV)  [158,160) wot (dead after out-proj)
    //  [160,168) w1t  [168,176) w2t        (live through FFN)
    //  hb = [32,160) 128MB                 (written by FFN1, after all above die)
    bf16_t* xb    = (bf16_t*)(ws + 0 * MB);
    bf16_t* ob    = (bf16_t*)(ws + 0 * MB);
    bf16_t* alnb  = (bf16_t*)(ws + 0 * MB);
    bf16_t* qkv   = (bf16_t*)(ws + 32 * MB);
    bf16_t* hb    = (bf16_t*)(ws + 32 * MB);
    bf16_t* vt_l  = (bf16_t*)(ws + 128 * MB);
    bf16_t* vt_g  = (bf16_t*)(ws + 144 * MB);
    bf16_t* wqkvt = (bf16_t*)(ws + 152 * MB);
    bf16_t* wot   = (bf16_t*)(ws + 158 * MB);
    bf16_t* w1t   = (bf16_t*)(ws + 160 * MB);
    bf16_t* w2t   = (bf16_t*)(ws + 168 * MB);

    dim3 tb(32, 8);
    transpose_convert<<<dim3(32, 32), tb, 0, stream>>>(Wq, wqkvt, 1024, 1024);
    transpose_convert<<<dim3(32, 32), tb, 0, stream>>>(Wk, wqkvt + 1024 * 1024, 1024, 1024);
    transpose_convert<<<dim3(32, 32), tb, 0, stream>>>(Wv, wqkvt + 2 * 1024 * 1024, 1024, 1024);
    transpose_convert<<<dim3(32, 32), tb, 0, stream>>>(Wo, wot, 1024, 1024);
    transpose_convert<<<dim3(128, 32), tb, 0, stream>>>(W1, w1t, 1024, 4096);
    transpose_convert<<<dim3(32, 128), tb, 0, stream>>>(W2, w2t, 4096, 1024);
    f32_to_bf16_vec<<<16384, 256, 0, stream>>>(src, xb, 4194304);

    // fused QKV: C[M][3072] = xb @ [Wq|Wk|Wv]^T, per-segment bias
    gemm_bt<256><<<dim3(64, 12), 512, 0, stream>>>(xb, wqkvt, bq, bk, bv,
        nullptr, nullptr, nullptr, qkv, 3072, 1024, 0);

    // V transpose prepass (local heads 0..8 over all toks; global heads 8..16
    // over the 1024 compacted keys)
    v_transpose<false><<<dim3(64, 8, 4), 256, 0, stream>>>(qkv, vt_l, 4096);
    v_transpose<true ><<<dim3(16, 8, 4), 256, 0, stream>>>(qkv, vt_g, 1024);

    mfma_attn<2,  false><<<dim3(32, 8, 4), 256, 0, stream>>>(qkv, vt_l, ob, 0);
    mfma_attn<16, true ><<<dim3(32, 8, 4), 256, 0, stream>>>(qkv, vt_g, ob, 8);

    // out-proj + src residual -> out (fp32)
    gemm_bt<256><<<dim3(64, 4), 512, 0, stream>>>(ob, wot, bo, nullptr, nullptr,
        src, nullptr, out, nullptr, 1024, 1024, 0);
    ln_kernel<<<16384, 256, 0, stream>>>(out, g1, be1, nullptr, alnb);

    // FFN unchunked: hb spans [32,160) (qkv/vt/wqkvt/wot all dead by now).
    // FFN1: M=16384 N=4096 (grid 1024 = 4 full passes). FFN2: BN=256,
    // grid 64x4 = 256 blocks = exactly 1 pass (was BN=128 x 2 chunks).
    gemm_bt<256><<<dim3(64, 16), 512, 0, stream>>>(alnb, w1t, b1, nullptr, nullptr,
        nullptr, nullptr, nullptr, hb, 4096, 1024, 1);
    gemm_bt<256><<<dim3(64, 4), 512, 0, stream>>>(hb, w2t, b2, nullptr, nullptr,
        nullptr, alnb, out, nullptr, 1024, 4096, 0);
    ln_kernel<<<16384, 256, 0, stream>>>(out, g2, be2, out, nullptr);

    (void)in_sizes; (void)n_in; (void)out_size; (void)ws_size;
}